// Round 11
// baseline (586.571 us; speedup 1.0000x reference)
//
#include <hip/hip_runtime.h>

#define BLK 256
#define CH 8192           // edges per k_binA block (32 KB LDS sort buffer)
#define BSHIFT 12         // col bucket = col >> 12, 4096 nodes per bucket
#define BRANGE 4096
#define BMASK 4095
#define NSEG 4            // row segments (key = seg*NB + colbucket)
#define NSB 512           // stats partial blocks

// ============ fused stats + (seg,colbucket) histogram ============

__global__ void k_stats_hist(const float* __restrict__ x, int n,
                             const int* __restrict__ row, const int* __restrict__ col,
                             int E, int NB, int NKEY, int segshift,
                             double* __restrict__ partials, int* __restrict__ bhist) {
    __shared__ int h[1024];
    for (int j = threadIdx.x; j < 1024; j += blockDim.x) h[j] = 0;
    __syncthreads();
    int stride = gridDim.x * blockDim.x;
    int gtid = blockIdx.x * blockDim.x + threadIdx.x;

    int nqe = E >> 2;
    const int4* rv = reinterpret_cast<const int4*>(row);
    const int4* cv = reinterpret_cast<const int4*>(col);
    for (int q = gtid; q < nqe; q += stride) {
        int4 r = rv[q]; int4 c = cv[q];
        atomicAdd(&h[(r.x >> segshift) * NB + (c.x >> BSHIFT)], 1);
        atomicAdd(&h[(r.y >> segshift) * NB + (c.y >> BSHIFT)], 1);
        atomicAdd(&h[(r.z >> segshift) * NB + (c.z >> BSHIFT)], 1);
        atomicAdd(&h[(r.w >> segshift) * NB + (c.w >> BSHIFT)], 1);
    }
    if (blockIdx.x == 0) {
        for (int e = (nqe << 2) + threadIdx.x; e < E; e += blockDim.x)
            atomicAdd(&h[(row[e] >> segshift) * NB + (col[e] >> BSHIFT)], 1);
    }

    float s0 = 0.f, s1 = 0.f, s2 = 0.f, s3 = 0.f, s4 = 0.f;
    int nv = n >> 1;
    for (int i = gtid; i < nv; i += stride) {
        float4 v = reinterpret_cast<const float4*>(x)[i];
        s0 += v.x + v.z; s1 += v.y + v.w;
        s2 += v.x * v.x + v.z * v.z;
        s3 += v.y * v.y + v.w * v.w;
        s4 += v.x * v.y + v.z * v.w;
    }
    if (blockIdx.x == 0 && threadIdx.x == 0 && (n & 1)) {
        float2 v = reinterpret_cast<const float2*>(x)[n - 1];
        s0 += v.x; s1 += v.y; s2 += v.x * v.x; s3 += v.y * v.y; s4 += v.x * v.y;
    }
    for (int off = 32; off; off >>= 1) {
        s0 += __shfl_down(s0, off);
        s1 += __shfl_down(s1, off);
        s2 += __shfl_down(s2, off);
        s3 += __shfl_down(s3, off);
        s4 += __shfl_down(s4, off);
    }
    __shared__ double lds[4][5];
    int wid = threadIdx.x >> 6;
    if ((threadIdx.x & 63) == 0) {
        lds[wid][0] = s0; lds[wid][1] = s1; lds[wid][2] = s2;
        lds[wid][3] = s3; lds[wid][4] = s4;
    }
    __syncthreads();
    if (threadIdx.x == 0) {
        double t0 = 0, t1 = 0, t2 = 0, t3 = 0, t4 = 0;
        for (int w = 0; w < 4; ++w) {
            t0 += lds[w][0]; t1 += lds[w][1]; t2 += lds[w][2];
            t3 += lds[w][3]; t4 += lds[w][4];
        }
        double* o = partials + (size_t)blockIdx.x * 5;
        o[0] = t0; o[1] = t1; o[2] = t2; o[3] = t3; o[4] = t4;
    }
    for (int j = threadIdx.x; j < NKEY; j += blockDim.x)
        if (h[j]) atomicAdd(&bhist[j], h[j]);
}

// ===== params: partial reduce + closed-form math + NKEY-bin scan (fused) =====

__global__ void k_params(const double* __restrict__ partials, int np,
                         const int* __restrict__ bhist, int NKEY,
                         int* __restrict__ gbase, int* __restrict__ cursor,
                         const float* lin_w, const float* lin_b,
                         const float* gn_w, const float* gn_b, const float* gn_ms,
                         const float* gcn_w, const float* gcn_b,
                         const float* fc1_w, const float* fc1_b,
                         const float* fc2_w, const float* fc2_b,
                         int n, float* __restrict__ P) {
    int tid = threadIdx.x;
    if (bhist) {
        __shared__ int si[256];
        int b4 = tid * 4;
        int v0 = (b4     < NKEY) ? bhist[b4]     : 0;
        int v1 = (b4 + 1 < NKEY) ? bhist[b4 + 1] : 0;
        int v2 = (b4 + 2 < NKEY) ? bhist[b4 + 2] : 0;
        int v3 = (b4 + 3 < NKEY) ? bhist[b4 + 3] : 0;
        int sum = v0 + v1 + v2 + v3;
        si[tid] = sum; __syncthreads();
        for (int off = 1; off < 256; off <<= 1) {
            int t = (tid >= off) ? si[tid - off] : 0;
            __syncthreads();
            si[tid] += t;
            __syncthreads();
        }
        int base = si[tid] - sum;
        if (b4     < NKEY) { gbase[b4]     = base;            cursor[b4]     = base; }
        if (b4 + 1 < NKEY) { gbase[b4 + 1] = base + v0;       cursor[b4 + 1] = base + v0; }
        if (b4 + 2 < NKEY) { gbase[b4 + 2] = base + v0 + v1;  cursor[b4 + 2] = base + v0 + v1; }
        if (b4 + 3 < NKEY) { gbase[b4 + 3] = base + v0 + v1 + v2; cursor[b4 + 3] = base + v0 + v1 + v2; }
        if (tid == 255) gbase[NKEY] = si[255];
        __syncthreads();
    }
    double a0 = 0, a1 = 0, a2 = 0, a3 = 0, a4 = 0;
    for (int i = tid; i < np; i += blockDim.x) {
        const double* q = partials + (size_t)i * 5;
        a0 += q[0]; a1 += q[1]; a2 += q[2]; a3 += q[3]; a4 += q[4];
    }
    for (int off = 32; off; off >>= 1) {
        a0 += __shfl_down(a0, off);
        a1 += __shfl_down(a1, off);
        a2 += __shfl_down(a2, off);
        a3 += __shfl_down(a3, off);
        a4 += __shfl_down(a4, off);
    }
    __shared__ double red[4][5];
    int wid = tid >> 6;
    if ((tid & 63) == 0) {
        red[wid][0] = a0; red[wid][1] = a1; red[wid][2] = a2;
        red[wid][3] = a3; red[wid][4] = a4;
    }
    __syncthreads();
    if (tid != 0) return;
    double Sx0 = 0, Sx1 = 0, Sxx = 0, Syy = 0, Sxy = 0;
    for (int w = 0; w < 4; ++w) {
        Sx0 += red[w][0]; Sx1 += red[w][1]; Sxx += red[w][2];
        Syy += red[w][3]; Sxy += red[w][4];
    }
    double N = (double)n;
    for (int c = 0; c < 2; ++c) {
        double L0 = lin_w[c * 2], L1 = lin_w[c * 2 + 1], lb = lin_b[c];
        double m   = (L0 * Sx0 + L1 * Sx1) / N + lb;
        double Eh2 = (L0 * L0 * Sxx + L1 * L1 * Syy + 2.0 * L0 * L1 * Sxy
                      + 2.0 * lb * (L0 * Sx0 + L1 * Sx1)) / N + lb * lb;
        double s   = gn_ms[c];
        double var = Eh2 - 2.0 * s * m * m + s * s * m * m;
        double inv = 1.0 / sqrt(var + 2.0);   // eps = D = 2 (arg-order quirk)
        double gam = gn_w[c];
        P[c * 2 + 0] = (float)(gam * inv * L0);
        P[c * 2 + 1] = (float)(gam * inv * L1);
        P[4 + c]     = (float)(gam * inv * (lb - m * s) + gn_b[c]);
    }
    P[6] = gcn_w[0]; P[7] = gcn_w[1]; P[8] = gcn_w[2]; P[9] = gcn_w[3];
    P[10] = gcn_b[0]; P[11] = gcn_b[1];
    double b0 = 0, b1 = 0, bb = 0;
    for (int j = 0; j < 64; ++j) { b0 += fc1_w[2 * j]; b1 += fc1_w[2 * j + 1]; bb += fc1_b[j]; }
    b0 /= 64.0; b1 /= 64.0; bb /= 64.0;
    double S00 = 0, S01 = 0, S11 = 0, Sb0 = 0, Sb1 = 0, Sbb = 0;
    double M00 = 0, M01 = 0, M10 = 0, M11 = 0, t0 = 0, t1 = 0;
    for (int j = 0; j < 64; ++j) {
        double w0 = fc1_w[2 * j] - b0, w1 = fc1_w[2 * j + 1] - b1, b = fc1_b[j] - bb;
        S00 += w0 * w0; S01 += w0 * w1; S11 += w1 * w1;
        Sb0 += w0 * b;  Sb1 += w1 * b;  Sbb += b * b;
        double f0 = fc2_w[j], f1 = fc2_w[64 + j];
        M00 += f0 * w0; M01 += f0 * w1; t0 += f0 * b;
        M10 += f1 * w0; M11 += f1 * w1; t1 += f1 * b;
    }
    P[12] = (float)(S00 / 64.0); P[13] = (float)(S01 / 64.0); P[14] = (float)(S11 / 64.0);
    P[15] = (float)(Sb0 / 64.0); P[16] = (float)(Sb1 / 64.0); P[17] = (float)(Sbb / 64.0);
    P[18] = (float)M00; P[19] = (float)M01; P[20] = (float)M10; P[21] = (float)M11;
    P[22] = (float)t0;  P[23] = (float)t1;
    P[24] = fc2_b[0];   P[25] = fc2_b[1];
}

// ============ binning: block-local counting sort over (seg,colb) keys ============

__global__ __launch_bounds__(256) void k_binA(const int* __restrict__ row,
                                              const int* __restrict__ col, int E,
                                              int NB, int NKEY, int segshift,
                                              int* __restrict__ cursor,
                                              unsigned* __restrict__ staging) {
    __shared__ unsigned buf[CH];                  // 32 KB
    __shared__ int h[1024], bb[1024], lcur[1024]; // 12 KB
    __shared__ int si[256];
    int tid = threadIdx.x;
    int start = blockIdx.x * CH;
    int end = start + CH; if (end > E) end = E;
    for (int j = tid; j < 1024; j += 256) h[j] = 0;
    __syncthreads();
    for (int e = start + tid; e < end; e += 256)
        atomicAdd(&h[(row[e] >> segshift) * NB + (col[e] >> BSHIFT)], 1);
    __syncthreads();
    int b4 = tid * 4;
    int v0 = h[b4], v1 = h[b4 + 1], v2 = h[b4 + 2], v3 = h[b4 + 3];
    int sum = v0 + v1 + v2 + v3;
    si[tid] = sum; __syncthreads();
    for (int off = 1; off < 256; off <<= 1) {
        int t = (tid >= off) ? si[tid - off] : 0;
        __syncthreads();
        si[tid] += t;
        __syncthreads();
    }
    int base = si[tid] - sum;
    bb[b4]     = base;
    bb[b4 + 1] = base + v0;
    bb[b4 + 2] = base + v0 + v1;
    bb[b4 + 3] = base + v0 + v1 + v2;
    lcur[b4]     = (b4     < NKEY && v0) ? atomicAdd(&cursor[b4],     v0) : 0;
    lcur[b4 + 1] = (b4 + 1 < NKEY && v1) ? atomicAdd(&cursor[b4 + 1], v1) : 0;
    lcur[b4 + 2] = (b4 + 2 < NKEY && v2) ? atomicAdd(&cursor[b4 + 2], v2) : 0;
    lcur[b4 + 3] = (b4 + 3 < NKEY && v3) ? atomicAdd(&cursor[b4 + 3], v3) : 0;
    __syncthreads();
    for (int e = start + tid; e < end; e += 256) {
        int r = row[e], c = col[e];
        int key = (r >> segshift) * NB + (c >> BSHIFT);
        unsigned w = ((unsigned)r << BSHIFT) | (unsigned)(c & BMASK);
        int slot = atomicAdd(&bb[key], 1);
        buf[slot] = w;
    }
    __syncthreads();
    int wid = tid >> 6, lane = tid & 63;
    for (int k = wid; k < NKEY; k += 4) {
        int m = h[k];
        if (!m) continue;
        int lb = bb[k] - m;                       // bb advanced to base+m
        int g = lcur[k];
        for (int j = lane; j < m; j += 64)
            staging[g + j] = buf[lb + j];
    }
}

// ---- helper: histogram col-low over a staging range ----
__device__ __forceinline__ void hist_range(const unsigned* __restrict__ staging,
                                           int s, int e, int* hist, int tid) {
    int pre = (4 - (s & 3)) & 3; int cnt = e - s; if (pre > cnt) pre = cnt;
    for (int i = s + tid; i < s + pre; i += 1024)
        atomicAdd(&hist[staging[i] & BMASK], 1);
    int vs = s + pre;
    int nq = (e - vs) >> 2;
    const uint4* sv = reinterpret_cast<const uint4*>(staging + vs);
    for (int q = tid; q < nq; q += 1024) {
        uint4 w = sv[q];
        atomicAdd(&hist[w.x & BMASK], 1);
        atomicAdd(&hist[w.y & BMASK], 1);
        atomicAdd(&hist[w.z & BMASK], 1);
        atomicAdd(&hist[w.w & BMASK], 1);
    }
    for (int i = vs + (nq << 2) + tid; i < e; i += 1024)
        atomicAdd(&hist[staging[i] & BMASK], 1);
}

// fused: per-bucket degree histogram (over NSEG ranges) + p-prep
__global__ __launch_bounds__(1024) void k_degprep(const unsigned* __restrict__ staging,
                                                  const int* __restrict__ gbase,
                                                  const float* __restrict__ x,
                                                  const float* __restrict__ P,
                                                  int n, int NB, int* __restrict__ deg,
                                                  float2* __restrict__ p) {
    __shared__ int hist[BRANGE];
    int tid = threadIdx.x;
    for (int j = tid; j < BRANGE; j += 1024) hist[j] = 0;
    __syncthreads();
    for (int s = 0; s < NSEG; ++s) {
        int idx = s * NB + blockIdx.x;
        hist_range(staging, gbase[idx], gbase[idx + 1], hist, tid);
    }
    __syncthreads();
    float A00 = P[0], A01 = P[1], A10 = P[2], A11 = P[3], q0 = P[4], q1 = P[5];
    float g00 = P[6], g01 = P[7], g10 = P[8], g11 = P[9];
    int nb = blockIdx.x << BSHIFT;
    int lim = n - nb; if (lim > BRANGE) lim = BRANGE;
    for (int j = tid; j < lim; j += 1024) {
        int d = hist[j];
        deg[nb + j] = d;
        float2 v = reinterpret_cast<const float2*>(x)[nb + j];
        float gg0 = fmaxf(fmaf(A00, v.x, fmaf(A01, v.y, q0)), 0.f);
        float gg1 = fmaxf(fmaf(A10, v.x, fmaf(A11, v.y, q1)), 0.f);
        float hw0 = g00 * gg0 + g01 * gg1;
        float hw1 = g10 * gg0 + g11 * gg1;
        float degf = (float)d + 1.0f;
        float dis = rsqrtf(degf);
        p[nb + j] = make_float2(dis * hw0, dis * hw1);
    }
}

#define AGG2(W, PV) \
    atomicAdd(&acc[2 * ((W) & BMASK)],     (PV).x); \
    atomicAdd(&acc[2 * ((W) & BMASK) + 1], (PV).y);

// seg-swept aggregation (L2-resident p slices, 16-deep MLP) + fused epilogue
__global__ __launch_bounds__(1024) void k_aggfin(
        const unsigned* __restrict__ staging, const int* __restrict__ gbase,
        const float2* __restrict__ p, const float* __restrict__ x,
        const int* __restrict__ deg, const int* __restrict__ batch,
        const float* __restrict__ Pp, int n, int NB,
        float* __restrict__ gsum, float* __restrict__ gcnt) {
    __shared__ float acc[2 * BRANGE];             // 32 KB
    int tid = threadIdx.x;
    for (int j = tid; j < 2 * BRANGE; j += 1024) acc[j] = 0.f;
    __syncthreads();
    for (int s = 0; s < NSEG; ++s) {
        int idx = s * NB + blockIdx.x;
        int rs = gbase[idx], re = gbase[idx + 1];
        int cnt = re - rs;
        int pre = (4 - (rs & 3)) & 3; if (pre > cnt) pre = cnt;
        for (int i = rs + tid; i < rs + pre; i += 1024) {
            unsigned w = staging[i]; float2 pv = p[w >> BSHIFT];
            AGG2(w, pv)
        }
        int vs = rs + pre;
        int nq = (re - vs) >> 2;
        const uint4* sv = reinterpret_cast<const uint4*>(staging + vs);
        int qtr = nq >> 2;                        // 4 quarter-streams -> 16 gathers in flight
        for (int q = tid; q < qtr; q += 1024) {
            uint4 wa = sv[q];
            uint4 wb = sv[q + qtr];
            uint4 wc = sv[q + 2 * qtr];
            uint4 wd = sv[q + 3 * qtr];
            float2 a0 = p[wa.x >> BSHIFT], a1 = p[wa.y >> BSHIFT];
            float2 a2 = p[wa.z >> BSHIFT], a3 = p[wa.w >> BSHIFT];
            float2 b0 = p[wb.x >> BSHIFT], b1 = p[wb.y >> BSHIFT];
            float2 b2 = p[wb.z >> BSHIFT], b3 = p[wb.w >> BSHIFT];
            float2 c0 = p[wc.x >> BSHIFT], c1 = p[wc.y >> BSHIFT];
            float2 c2 = p[wc.z >> BSHIFT], c3 = p[wc.w >> BSHIFT];
            float2 d0 = p[wd.x >> BSHIFT], d1 = p[wd.y >> BSHIFT];
            float2 d2 = p[wd.z >> BSHIFT], d3 = p[wd.w >> BSHIFT];
            AGG2(wa.x, a0) AGG2(wa.y, a1) AGG2(wa.z, a2) AGG2(wa.w, a3)
            AGG2(wb.x, b0) AGG2(wb.y, b1) AGG2(wb.z, b2) AGG2(wb.w, b3)
            AGG2(wc.x, c0) AGG2(wc.y, c1) AGG2(wc.z, c2) AGG2(wc.w, c3)
            AGG2(wd.x, d0) AGG2(wd.y, d1) AGG2(wd.z, d2) AGG2(wd.w, d3)
        }
        for (int q = (qtr << 2) + tid; q < nq; q += 1024) {
            uint4 w = sv[q];
            float2 p0 = p[w.x >> BSHIFT], p1 = p[w.y >> BSHIFT];
            float2 p2 = p[w.z >> BSHIFT], p3 = p[w.w >> BSHIFT];
            AGG2(w.x, p0) AGG2(w.y, p1) AGG2(w.z, p2) AGG2(w.w, p3)
        }
        for (int i = vs + (nq << 2) + tid; i < re; i += 1024) {
            unsigned w = staging[i]; float2 pv = p[w >> BSHIFT];
            AGG2(w, pv)
        }
    }
    __syncthreads();

    // ---- fused epilogue: per-node finish + scatter_mean ----
    float A00 = Pp[0], A01 = Pp[1], A10 = Pp[2], A11 = Pp[3], q0f = Pp[4], q1f = Pp[5];
    float g00 = Pp[6], g01 = Pp[7], g10 = Pp[8], g11 = Pp[9];
    float gb0 = Pp[10], gb1 = Pp[11];
    float S00 = Pp[12], S01 = Pp[13], S11 = Pp[14], Sb0 = Pp[15], Sb1 = Pp[16], Sbb = Pp[17];
    float M00 = Pp[18], M01 = Pp[19], M10 = Pp[20], M11 = Pp[21];
    float t0 = Pp[22], t1 = Pp[23], fb0 = Pp[24], fb1 = Pp[25];
    int nb = blockIdx.x << BSHIFT;
    int lim = n - nb; if (lim > BRANGE) lim = BRANGE;
    for (int j = tid; j < lim; j += 1024) {
        int i = nb + j;
        float2 v = reinterpret_cast<const float2*>(x)[i];
        float g0 = fmaxf(fmaf(A00, v.x, fmaf(A01, v.y, q0f)), 0.f);
        float g1 = fmaxf(fmaf(A10, v.x, fmaf(A11, v.y, q1f)), 0.f);
        float hw0 = g00 * g0 + g01 * g1;
        float hw1 = g10 * g0 + g11 * g1;
        float degf = (float)deg[i] + 1.0f;
        float dis = rsqrtf(degf);
        float a0v = acc[2 * j], a1v = acc[2 * j + 1];
        float c0 = dis * a0v + hw0 / degf + gb0 + g0;
        float c1 = dis * a1v + hw1 / degf + gb1 + g1;
        float vq = S00 * c0 * c0 + 2.f * S01 * c0 * c1 + S11 * c1 * c1
                 + 2.f * Sb0 * c0 + 2.f * Sb1 * c1 + Sbb;
        float inv = rsqrtf(vq + 64.0f);   // eps = H = 64 (arg-order quirk)
        float o0 = inv * (M00 * c0 + M01 * c1 + t0) + fb0;
        float o1 = inv * (M10 * c0 + M11 * c1 + t1) + fb1;
        int bg = batch[i];
        unsigned long long act = __ballot(true);
        if (act == ~0ull) {
            int b0 = __shfl(bg, 0);
            if (__all(bg == b0)) {
                float s0 = o0, s1 = o1;
                for (int off = 32; off; off >>= 1) {
                    s0 += __shfl_down(s0, off);
                    s1 += __shfl_down(s1, off);
                }
                if ((tid & 63) == 0) {
                    atomicAdd(&gsum[2 * b0], s0);
                    atomicAdd(&gsum[2 * b0 + 1], s1);
                    atomicAdd(&gcnt[b0], 64.0f);
                }
            } else {
                atomicAdd(&gsum[2 * bg], o0);
                atomicAdd(&gsum[2 * bg + 1], o1);
                atomicAdd(&gcnt[bg], 1.0f);
            }
        } else {
            atomicAdd(&gsum[2 * bg], o0);
            atomicAdd(&gsum[2 * bg + 1], o1);
            atomicAdd(&gcnt[bg], 1.0f);
        }
    }
}

__global__ void k_div(const float* __restrict__ gsum, const float* __restrict__ gcnt,
                      float* __restrict__ out, int G) {
    int g = blockIdx.x * blockDim.x + threadIdx.x;
    if (g < G) {
        float c = fmaxf(gcnt[g], 1.0f);
        out[2 * g]     = gsum[2 * g] / c;
        out[2 * g + 1] = gsum[2 * g + 1] / c;
    }
}

// ======================= fallback (global-atomic) kernels =======================

__global__ void k_stats(const float* __restrict__ x, int n, double* __restrict__ partials) {
    float s0 = 0.f, s1 = 0.f, s2 = 0.f, s3 = 0.f, s4 = 0.f;
    int nv = n >> 1;
    int stride = gridDim.x * blockDim.x;
    for (int i = blockIdx.x * blockDim.x + threadIdx.x; i < nv; i += stride) {
        float4 v = reinterpret_cast<const float4*>(x)[i];
        s0 += v.x + v.z; s1 += v.y + v.w;
        s2 += v.x * v.x + v.z * v.z;
        s3 += v.y * v.y + v.w * v.w;
        s4 += v.x * v.y + v.z * v.w;
    }
    if (blockIdx.x == 0 && threadIdx.x == 0 && (n & 1)) {
        float2 v = reinterpret_cast<const float2*>(x)[n - 1];
        s0 += v.x; s1 += v.y; s2 += v.x * v.x; s3 += v.y * v.y; s4 += v.x * v.y;
    }
    for (int off = 32; off; off >>= 1) {
        s0 += __shfl_down(s0, off);
        s1 += __shfl_down(s1, off);
        s2 += __shfl_down(s2, off);
        s3 += __shfl_down(s3, off);
        s4 += __shfl_down(s4, off);
    }
    __shared__ double lds[4][5];
    int wid = threadIdx.x >> 6;
    if ((threadIdx.x & 63) == 0) {
        lds[wid][0] = s0; lds[wid][1] = s1; lds[wid][2] = s2;
        lds[wid][3] = s3; lds[wid][4] = s4;
    }
    __syncthreads();
    if (threadIdx.x == 0) {
        double t0 = 0, t1 = 0, t2 = 0, t3 = 0, t4 = 0;
        for (int w = 0; w < 4; ++w) {
            t0 += lds[w][0]; t1 += lds[w][1]; t2 += lds[w][2];
            t3 += lds[w][3]; t4 += lds[w][4];
        }
        double* o = partials + (size_t)blockIdx.x * 5;
        o[0] = t0; o[1] = t1; o[2] = t2; o[3] = t3; o[4] = t4;
    }
}

__global__ void k_prep(const float* __restrict__ x, const int* __restrict__ deg,
                       const float* __restrict__ P, int n, float2* __restrict__ p) {
    int stride = gridDim.x * blockDim.x;
    float A00 = P[0], A01 = P[1], A10 = P[2], A11 = P[3], q0 = P[4], q1 = P[5];
    float g00 = P[6], g01 = P[7], g10 = P[8], g11 = P[9];
    for (int i = blockIdx.x * blockDim.x + threadIdx.x; i < n; i += stride) {
        float2 v = reinterpret_cast<const float2*>(x)[i];
        float g0 = fmaxf(fmaf(A00, v.x, fmaf(A01, v.y, q0)), 0.f);
        float g1 = fmaxf(fmaf(A10, v.x, fmaf(A11, v.y, q1)), 0.f);
        float hw0 = g00 * g0 + g01 * g1;
        float hw1 = g10 * g0 + g11 * g1;
        float degf = (float)deg[i] + 1.0f;
        float dis = rsqrtf(degf);
        p[i] = make_float2(dis * hw0, dis * hw1);
    }
}

__global__ void k_deg(const int* __restrict__ col, int E, int* __restrict__ deg) {
    int nq = (E + 3) >> 2;
    int q = blockIdx.x * blockDim.x + threadIdx.x;
    if (q >= nq) return;
    int base = q << 2;
    if (base + 3 < E) {
        int4 c = reinterpret_cast<const int4*>(col)[q];
        atomicAdd(&deg[c.x], 1); atomicAdd(&deg[c.y], 1);
        atomicAdd(&deg[c.z], 1); atomicAdd(&deg[c.w], 1);
    } else {
        for (int e = base; e < E; ++e) atomicAdd(&deg[col[e]], 1);
    }
}

__global__ void k_edge(const int* __restrict__ row, const int* __restrict__ col, int E,
                       const float2* __restrict__ p, float* __restrict__ agg) {
    int nq = (E + 3) >> 2;
    int q = blockIdx.x * blockDim.x + threadIdx.x;
    if (q >= nq) return;
    int base = q << 2;
    if (base + 3 < E) {
        int4 r = reinterpret_cast<const int4*>(row)[q];
        int4 c = reinterpret_cast<const int4*>(col)[q];
        float2 p0 = p[r.x], p1 = p[r.y], p2 = p[r.z], p3 = p[r.w];
        atomicAdd(&agg[2 * c.x], p0.x); atomicAdd(&agg[2 * c.x + 1], p0.y);
        atomicAdd(&agg[2 * c.y], p1.x); atomicAdd(&agg[2 * c.y + 1], p1.y);
        atomicAdd(&agg[2 * c.z], p2.x); atomicAdd(&agg[2 * c.z + 1], p2.y);
        atomicAdd(&agg[2 * c.w], p3.x); atomicAdd(&agg[2 * c.w + 1], p3.y);
    } else {
        for (int e = base; e < E; ++e) {
            float2 pv = p[row[e]];
            atomicAdd(&agg[2 * col[e]], pv.x);
            atomicAdd(&agg[2 * col[e] + 1], pv.y);
        }
    }
}

__global__ void k_final(const float* __restrict__ x, const int* __restrict__ deg,
                        const float* __restrict__ agg, const int* __restrict__ batch,
                        const float* __restrict__ P, int n,
                        float* __restrict__ gsum, float* __restrict__ gcnt) {
    int i = blockIdx.x * blockDim.x + threadIdx.x;
    bool valid = i < n;
    float A00 = P[0], A01 = P[1], A10 = P[2], A11 = P[3], q0 = P[4], q1 = P[5];
    float g00 = P[6], g01 = P[7], g10 = P[8], g11 = P[9];
    float gb0 = P[10], gb1 = P[11];
    float S00 = P[12], S01 = P[13], S11 = P[14], Sb0 = P[15], Sb1 = P[16], Sbb = P[17];
    float M00 = P[18], M01 = P[19], M10 = P[20], M11 = P[21];
    float t0 = P[22], t1 = P[23], fb0 = P[24], fb1 = P[25];

    float o0 = 0.f, o1 = 0.f;
    int b = 0;
    if (valid) {
        float2 v = reinterpret_cast<const float2*>(x)[i];
        float g0 = fmaxf(fmaf(A00, v.x, fmaf(A01, v.y, q0)), 0.f);
        float g1 = fmaxf(fmaf(A10, v.x, fmaf(A11, v.y, q1)), 0.f);
        float hw0 = g00 * g0 + g01 * g1;
        float hw1 = g10 * g0 + g11 * g1;
        float degf = (float)deg[i] + 1.0f;
        float dis = rsqrtf(degf);
        float a0 = agg[2 * i], a1 = agg[2 * i + 1];
        float c0 = dis * a0 + hw0 / degf + gb0 + g0;
        float c1 = dis * a1 + hw1 / degf + gb1 + g1;
        float vq = S00 * c0 * c0 + 2.f * S01 * c0 * c1 + S11 * c1 * c1
                 + 2.f * Sb0 * c0 + 2.f * Sb1 * c1 + Sbb;
        float inv = rsqrtf(vq + 64.0f);
        o0 = inv * (M00 * c0 + M01 * c1 + t0) + fb0;
        o1 = inv * (M10 * c0 + M11 * c1 + t1) + fb1;
        b = batch[i];
    }
    unsigned long long act = __ballot(valid);
    if (act == ~0ull) {
        int b0 = __shfl(b, 0);
        if (__all(b == b0)) {
            float s0 = o0, s1 = o1;
            for (int off = 32; off; off >>= 1) {
                s0 += __shfl_down(s0, off);
                s1 += __shfl_down(s1, off);
            }
            if ((threadIdx.x & 63) == 0) {
                atomicAdd(&gsum[2 * b0], s0);
                atomicAdd(&gsum[2 * b0 + 1], s1);
                atomicAdd(&gcnt[b0], 64.0f);
            }
        } else {
            atomicAdd(&gsum[2 * b], o0);
            atomicAdd(&gsum[2 * b + 1], o1);
            atomicAdd(&gcnt[b], 1.0f);
        }
    } else if (valid) {
        atomicAdd(&gsum[2 * b], o0);
        atomicAdd(&gsum[2 * b + 1], o1);
        atomicAdd(&gcnt[b], 1.0f);
    }
}

// ======================= launcher =======================

extern "C" void kernel_launch(void* const* d_in, const int* in_sizes, int n_in,
                              void* d_out, int out_size, void* d_ws, size_t ws_size,
                              hipStream_t stream) {
    const float* x      = (const float*)d_in[0];
    const float* lin_w  = (const float*)d_in[1];
    const float* lin_b  = (const float*)d_in[2];
    const float* gn_w   = (const float*)d_in[3];
    const float* gn_b   = (const float*)d_in[4];
    const float* gn_ms  = (const float*)d_in[5];
    const float* gcn_w  = (const float*)d_in[6];
    const float* gcn_b  = (const float*)d_in[7];
    const float* fc1_w  = (const float*)d_in[8];
    const float* fc1_b  = (const float*)d_in[9];
    const float* fc2_w  = (const float*)d_in[10];
    const float* fc2_b  = (const float*)d_in[11];
    const int*   ei     = (const int*)d_in[12];   // [2, E] row-major
    const int*   batch  = (const int*)d_in[13];

    int n = in_sizes[0] / 2;
    int E = in_sizes[12] / 2;
    int G = out_size / 2;
    const int* row = ei;
    const int* col = ei + E;

    char* ws = (char*)d_ws;
    int nb_nodes = (n + BLK - 1) / BLK;
    int NB = (n + BRANGE - 1) >> BSHIFT;
    int NKEY = NSEG * NB;
    int segshift = 0;
    while (((unsigned)(n - 1) >> segshift) >= (unsigned)NSEG) ++segshift;

    // fast-path layout
    size_t zero_end  = 16384 + (size_t)12 * G;               // hdr + gsum + gcnt
    size_t part_off  = (zero_end + 255) & ~(size_t)255;
    size_t deg_off   = (part_off + (size_t)40 * NSB + 255) & ~(size_t)255;
    size_t p_off     = deg_off + (size_t)4 * n;
    size_t stag_off  = p_off + (size_t)8 * n;
    size_t need      = stag_off + (size_t)4 * E;

    bool fast = (n <= (1 << 20)) && (NB <= 253) && (NKEY <= 1020) &&
                ((E & 3) == 0) && (need <= ws_size) &&
                (zero_end <= 16384 + 12288);

    if (fast) {
        float*    P       = (float*)(ws + 64);
        int*      bhist   = (int*)(ws + 4096);    // NKEY ints
        int*      gbase   = (int*)(ws + 8192);    // NKEY+1 ints
        int*      cursor  = (int*)(ws + 12288);   // NKEY ints
        float*    gsum    = (float*)(ws + 16384);
        float*    gcnt    = (float*)(ws + 16384 + (size_t)8 * G);
        double*   part    = (double*)(ws + part_off);
        int*      deg     = (int*)(ws + deg_off);
        float2*   p       = (float2*)(ws + p_off);
        unsigned* staging = (unsigned*)(ws + stag_off);

        hipMemsetAsync(d_ws, 0, zero_end, stream);

        int nbinA = (E + CH - 1) / CH;

        k_stats_hist<<<NSB, BLK, 0, stream>>>(x, n, row, col, E, NB, NKEY, segshift,
                                              part, bhist);
        k_params<<<1, 256, 0, stream>>>(part, NSB, bhist, NKEY, gbase, cursor,
                                        lin_w, lin_b, gn_w, gn_b, gn_ms,
                                        gcn_w, gcn_b, fc1_w, fc1_b, fc2_w, fc2_b, n, P);
        k_binA<<<nbinA, 256, 0, stream>>>(row, col, E, NB, NKEY, segshift,
                                          cursor, staging);
        k_degprep<<<NB, 1024, 0, stream>>>(staging, gbase, x, P, n, NB, deg, p);
        k_aggfin<<<NB, 1024, 0, stream>>>(staging, gbase, p, x, deg, batch,
                                          P, n, NB, gsum, gcnt);
        k_div<<<(G + BLK - 1) / BLK, BLK, 0, stream>>>(gsum, gcnt, (float*)d_out, G);
    } else {
        // fallback: global-atomic path
        float*  P     = (float*)(ws + 64);
        float*  gsum  = (float*)(ws + 4096);
        float*  gcnt  = (float*)(ws + 4096 + (size_t)8 * G);
        size_t fzero_end = 4096 + (size_t)12 * G;
        size_t fpart_off = (fzero_end + 255) & ~(size_t)255;
        size_t fdeg_off  = (fpart_off + (size_t)40 * NSB + 255) & ~(size_t)255;
        int*    deg   = (int*)(ws + fdeg_off);
        size_t fagg_off = fdeg_off + (size_t)4 * n;
        float*  agg   = (float*)(ws + fagg_off);
        size_t fp_off = fagg_off + (size_t)8 * n;
        float2* p     = (float2*)(ws + fp_off);
        double* part  = (double*)(ws + fpart_off);

        hipMemsetAsync(ws + 4096, 0, fzero_end - 4096, stream);
        hipMemsetAsync(ws + fdeg_off, 0, (size_t)12 * n, stream);

        int nq = (E + 3) >> 2;
        int nb_edge = (nq + BLK - 1) / BLK;

        k_stats<<<NSB, BLK, 0, stream>>>(x, n, part);
        k_deg<<<nb_edge, BLK, 0, stream>>>(col, E, deg);
        k_params<<<1, 256, 0, stream>>>(part, NSB, (const int*)nullptr, 0,
                                        (int*)nullptr, (int*)nullptr,
                                        lin_w, lin_b, gn_w, gn_b, gn_ms,
                                        gcn_w, gcn_b, fc1_w, fc1_b, fc2_w, fc2_b, n, P);
        k_prep<<<nb_nodes, BLK, 0, stream>>>(x, deg, P, n, p);
        k_edge<<<nb_edge, BLK, 0, stream>>>(row, col, E, p, agg);
        k_final<<<nb_nodes, BLK, 0, stream>>>(x, deg, agg, batch, P, n, gsum, gcnt);
        k_div<<<(G + BLK - 1) / BLK, BLK, 0, stream>>>(gsum, gcnt, (float*)d_out, G);
    }
}

// Round 12
// 477.862 us; speedup vs baseline: 1.2275x; 1.2275x over previous
//
#include <hip/hip_runtime.h>

#define BLK 256
#define CH 8192           // edges per k_binA block (32 KB LDS sort buffer)
#define BSHIFT 12         // col bucket = col >> 12, 4096 nodes per bucket
#define BRANGE 4096
#define BMASK 4095
#define NSEG 4            // row segments within each bucket (post-sort)
#define NSB 512           // stats partial blocks

// ============ fused stats + col-bucket histogram ============

__global__ void k_stats_hist(const float* __restrict__ x, int n,
                             const int* __restrict__ col, int E, int NB,
                             double* __restrict__ partials, int* __restrict__ bhist) {
    __shared__ int h[256];
    for (int j = threadIdx.x; j < 256; j += blockDim.x) h[j] = 0;
    __syncthreads();
    int stride = gridDim.x * blockDim.x;
    int gtid = blockIdx.x * blockDim.x + threadIdx.x;

    int nqe = E >> 2;
    for (int q = gtid; q < nqe; q += stride) {
        int4 c = reinterpret_cast<const int4*>(col)[q];
        atomicAdd(&h[c.x >> BSHIFT], 1);
        atomicAdd(&h[c.y >> BSHIFT], 1);
        atomicAdd(&h[c.z >> BSHIFT], 1);
        atomicAdd(&h[c.w >> BSHIFT], 1);
    }
    if (blockIdx.x == 0) {
        for (int e = (nqe << 2) + threadIdx.x; e < E; e += blockDim.x)
            atomicAdd(&h[col[e] >> BSHIFT], 1);
    }

    float s0 = 0.f, s1 = 0.f, s2 = 0.f, s3 = 0.f, s4 = 0.f;
    int nv = n >> 1;
    for (int i = gtid; i < nv; i += stride) {
        float4 v = reinterpret_cast<const float4*>(x)[i];
        s0 += v.x + v.z; s1 += v.y + v.w;
        s2 += v.x * v.x + v.z * v.z;
        s3 += v.y * v.y + v.w * v.w;
        s4 += v.x * v.y + v.z * v.w;
    }
    if (blockIdx.x == 0 && threadIdx.x == 0 && (n & 1)) {
        float2 v = reinterpret_cast<const float2*>(x)[n - 1];
        s0 += v.x; s1 += v.y; s2 += v.x * v.x; s3 += v.y * v.y; s4 += v.x * v.y;
    }
    for (int off = 32; off; off >>= 1) {
        s0 += __shfl_down(s0, off);
        s1 += __shfl_down(s1, off);
        s2 += __shfl_down(s2, off);
        s3 += __shfl_down(s3, off);
        s4 += __shfl_down(s4, off);
    }
    __shared__ double lds[4][5];
    int wid = threadIdx.x >> 6;
    if ((threadIdx.x & 63) == 0) {
        lds[wid][0] = s0; lds[wid][1] = s1; lds[wid][2] = s2;
        lds[wid][3] = s3; lds[wid][4] = s4;
    }
    __syncthreads();
    if (threadIdx.x == 0) {
        double t0 = 0, t1 = 0, t2 = 0, t3 = 0, t4 = 0;
        for (int w = 0; w < 4; ++w) {
            t0 += lds[w][0]; t1 += lds[w][1]; t2 += lds[w][2];
            t3 += lds[w][3]; t4 += lds[w][4];
        }
        double* o = partials + (size_t)blockIdx.x * 5;
        o[0] = t0; o[1] = t1; o[2] = t2; o[3] = t3; o[4] = t4;
    }
    for (int j = threadIdx.x; j < NB; j += blockDim.x)
        if (h[j]) atomicAdd(&bhist[j], h[j]);
}

// ===== params: partial reduce + closed-form math + 245-bin scan (fused) =====

__global__ void k_params(const double* __restrict__ partials, int np,
                         const int* __restrict__ bhist, int NB,
                         int* __restrict__ gbase, int* __restrict__ cursor,
                         const float* lin_w, const float* lin_b,
                         const float* gn_w, const float* gn_b, const float* gn_ms,
                         const float* gcn_w, const float* gcn_b,
                         const float* fc1_w, const float* fc1_b,
                         const float* fc2_w, const float* fc2_b,
                         int n, float* __restrict__ P) {
    int tid = threadIdx.x;
    if (bhist) {
        __shared__ int si[256];
        int hv = (tid < NB) ? bhist[tid] : 0;
        si[tid] = hv; __syncthreads();
        for (int off = 1; off < 256; off <<= 1) {
            int t = (tid >= off) ? si[tid - off] : 0;
            __syncthreads();
            si[tid] += t;
            __syncthreads();
        }
        if (tid < NB) { gbase[tid] = si[tid] - hv; cursor[tid] = si[tid] - hv; }
        if (tid == 0) gbase[NB] = si[255];
        __syncthreads();
    }
    double a0 = 0, a1 = 0, a2 = 0, a3 = 0, a4 = 0;
    for (int i = tid; i < np; i += blockDim.x) {
        const double* q = partials + (size_t)i * 5;
        a0 += q[0]; a1 += q[1]; a2 += q[2]; a3 += q[3]; a4 += q[4];
    }
    for (int off = 32; off; off >>= 1) {
        a0 += __shfl_down(a0, off);
        a1 += __shfl_down(a1, off);
        a2 += __shfl_down(a2, off);
        a3 += __shfl_down(a3, off);
        a4 += __shfl_down(a4, off);
    }
    __shared__ double red[4][5];
    int wid = tid >> 6;
    if ((tid & 63) == 0) {
        red[wid][0] = a0; red[wid][1] = a1; red[wid][2] = a2;
        red[wid][3] = a3; red[wid][4] = a4;
    }
    __syncthreads();
    if (tid != 0) return;
    double Sx0 = 0, Sx1 = 0, Sxx = 0, Syy = 0, Sxy = 0;
    for (int w = 0; w < 4; ++w) {
        Sx0 += red[w][0]; Sx1 += red[w][1]; Sxx += red[w][2];
        Syy += red[w][3]; Sxy += red[w][4];
    }
    double N = (double)n;
    for (int c = 0; c < 2; ++c) {
        double L0 = lin_w[c * 2], L1 = lin_w[c * 2 + 1], lb = lin_b[c];
        double m   = (L0 * Sx0 + L1 * Sx1) / N + lb;
        double Eh2 = (L0 * L0 * Sxx + L1 * L1 * Syy + 2.0 * L0 * L1 * Sxy
                      + 2.0 * lb * (L0 * Sx0 + L1 * Sx1)) / N + lb * lb;
        double s   = gn_ms[c];
        double var = Eh2 - 2.0 * s * m * m + s * s * m * m;
        double inv = 1.0 / sqrt(var + 2.0);   // eps = D = 2 (arg-order quirk)
        double gam = gn_w[c];
        P[c * 2 + 0] = (float)(gam * inv * L0);
        P[c * 2 + 1] = (float)(gam * inv * L1);
        P[4 + c]     = (float)(gam * inv * (lb - m * s) + gn_b[c]);
    }
    P[6] = gcn_w[0]; P[7] = gcn_w[1]; P[8] = gcn_w[2]; P[9] = gcn_w[3];
    P[10] = gcn_b[0]; P[11] = gcn_b[1];
    double b0 = 0, b1 = 0, bb = 0;
    for (int j = 0; j < 64; ++j) { b0 += fc1_w[2 * j]; b1 += fc1_w[2 * j + 1]; bb += fc1_b[j]; }
    b0 /= 64.0; b1 /= 64.0; bb /= 64.0;
    double S00 = 0, S01 = 0, S11 = 0, Sb0 = 0, Sb1 = 0, Sbb = 0;
    double M00 = 0, M01 = 0, M10 = 0, M11 = 0, t0 = 0, t1 = 0;
    for (int j = 0; j < 64; ++j) {
        double w0 = fc1_w[2 * j] - b0, w1 = fc1_w[2 * j + 1] - b1, b = fc1_b[j] - bb;
        S00 += w0 * w0; S01 += w0 * w1; S11 += w1 * w1;
        Sb0 += w0 * b;  Sb1 += w1 * b;  Sbb += b * b;
        double f0 = fc2_w[j], f1 = fc2_w[64 + j];
        M00 += f0 * w0; M01 += f0 * w1; t0 += f0 * b;
        M10 += f1 * w0; M11 += f1 * w1; t1 += f1 * b;
    }
    P[12] = (float)(S00 / 64.0); P[13] = (float)(S01 / 64.0); P[14] = (float)(S11 / 64.0);
    P[15] = (float)(Sb0 / 64.0); P[16] = (float)(Sb1 / 64.0); P[17] = (float)(Sbb / 64.0);
    P[18] = (float)M00; P[19] = (float)M01; P[20] = (float)M10; P[21] = (float)M11;
    P[22] = (float)t0;  P[23] = (float)t1;
    P[24] = fc2_b[0];   P[25] = fc2_b[1];
}

// ============ binning: 256-bin col counting sort (R9 form, unchanged) ============

__global__ __launch_bounds__(256) void k_binA(const int* __restrict__ row,
                                              const int* __restrict__ col, int E,
                                              int NB, int* __restrict__ cursor,
                                              unsigned* __restrict__ staging) {
    __shared__ unsigned buf[CH];                  // 32 KB
    __shared__ int h[256], si[256], lpos[256], lcur[256];
    int tid = threadIdx.x;
    int start = blockIdx.x * CH;
    int end = start + CH; if (end > E) end = E;
    h[tid] = 0;
    __syncthreads();
    for (int e = start + tid; e < end; e += 256)
        atomicAdd(&h[col[e] >> BSHIFT], 1);
    __syncthreads();
    int hv = h[tid];
    si[tid] = hv; __syncthreads();
    for (int off = 1; off < 256; off <<= 1) {
        int t = (tid >= off) ? si[tid - off] : 0;
        __syncthreads();
        si[tid] += t;
        __syncthreads();
    }
    lpos[tid] = si[tid] - hv;
    lcur[tid] = (tid < NB && hv) ? atomicAdd(&cursor[tid], hv) : 0;
    __syncthreads();
    for (int e = start + tid; e < end; e += 256) {
        int c = col[e];
        unsigned w = ((unsigned)row[e] << BSHIFT) | (unsigned)(c & BMASK);
        int slot = atomicAdd(&lpos[c >> BSHIFT], 1);
        buf[slot] = w;
    }
    __syncthreads();
    int wid = tid >> 6, lane = tid & 63;
    for (int b = wid; b < NB; b += 4) {
        int m = h[b];
        if (!m) continue;
        int lb = si[b] - m;
        int g = lcur[b];
        for (int k = lane; k < m; k += 64)
            staging[g + k] = buf[lb + k];
    }
}

// fused: degree histogram + p-prep + 4-seg row partition -> staging2 + soff
__global__ __launch_bounds__(1024) void k_degprep(const unsigned* __restrict__ staging,
                                                  const int* __restrict__ gbase,
                                                  const float* __restrict__ x,
                                                  const float* __restrict__ P,
                                                  int n, int segshift, int do_sort,
                                                  unsigned* __restrict__ staging2,
                                                  int* __restrict__ soff,
                                                  int* __restrict__ deg,
                                                  float2* __restrict__ p) {
    __shared__ int hist[BRANGE];
    __shared__ int segc[NSEG], segcur[NSEG];
    int tid = threadIdx.x;
    int lane = tid & 63;
    unsigned long long ltmask = (1ull << lane) - 1;
    for (int j = tid; j < BRANGE; j += 1024) hist[j] = 0;
    if (tid < NSEG) segc[tid] = 0;
    __syncthreads();
    int s = gbase[blockIdx.x], e = gbase[blockIdx.x + 1];

    // pass 1: col-low histogram + (optionally) seg counts via wave ballots
    for (int i = s + tid; i < e; i += 1024) {
        unsigned w = staging[i];
        atomicAdd(&hist[w & BMASK], 1);
        if (do_sort) {
            int sg = (int)((w >> BSHIFT) >> segshift);
            #pragma unroll
            for (int s2 = 0; s2 < NSEG; ++s2) {
                unsigned long long m = __ballot(sg == s2);
                if (sg == s2 && __popcll(m & ltmask) == 0)
                    atomicAdd(&segc[s2], (int)__popcll(m));
            }
        }
    }
    __syncthreads();

    if (do_sort) {
        if (tid == 0) {
            int a = 0;
            for (int s2 = 0; s2 < NSEG; ++s2) {
                soff[blockIdx.x * (NSEG + 1) + s2] = a;
                segcur[s2] = a;
                a += segc[s2];
            }
            soff[blockIdx.x * (NSEG + 1) + NSEG] = a;
        }
        __syncthreads();
        // pass 2: scatter into seg-partitioned staging2 (wave-aggregated place)
        for (int i = s + tid; i < e; i += 1024) {
            unsigned w = staging[i];
            int sg = (int)((w >> BSHIFT) >> segshift);
            #pragma unroll
            for (int s2 = 0; s2 < NSEG; ++s2) {
                unsigned long long m = __ballot(sg == s2);
                if (sg == s2) {
                    int prel = (int)__popcll(m & ltmask);
                    int ldr = (int)__ffsll((unsigned long long)m) - 1;
                    int base_ = 0;
                    if (prel == 0) base_ = atomicAdd(&segcur[s2], (int)__popcll(m));
                    base_ = __shfl(base_, ldr);
                    staging2[s + base_ + prel] = w;
                }
            }
        }
    }
    __syncthreads();

    float A00 = P[0], A01 = P[1], A10 = P[2], A11 = P[3], q0 = P[4], q1 = P[5];
    float g00 = P[6], g01 = P[7], g10 = P[8], g11 = P[9];
    int nb = blockIdx.x << BSHIFT;
    int lim = n - nb; if (lim > BRANGE) lim = BRANGE;
    for (int j = tid; j < lim; j += 1024) {
        int d = hist[j];
        deg[nb + j] = d;
        float2 v = reinterpret_cast<const float2*>(x)[nb + j];
        float gg0 = fmaxf(fmaf(A00, v.x, fmaf(A01, v.y, q0)), 0.f);
        float gg1 = fmaxf(fmaf(A10, v.x, fmaf(A11, v.y, q1)), 0.f);
        float hw0 = g00 * gg0 + g01 * gg1;
        float hw1 = g10 * gg0 + g11 * gg1;
        float degf = (float)d + 1.0f;
        float dis = rsqrtf(degf);
        p[nb + j] = make_float2(dis * hw0, dis * hw1);
    }
}

#define AGG2(W, PV) \
    atomicAdd(&acc[2 * ((W) & BMASK)],     (PV).x); \
    atomicAdd(&acc[2 * ((W) & BMASK) + 1], (PV).y);

__device__ __forceinline__ void agg_range(const unsigned* __restrict__ staging,
                                          int rs, int re,
                                          const float2* __restrict__ p,
                                          float* acc, int tid) {
    int cnt = re - rs;
    int pre = (4 - (rs & 3)) & 3; if (pre > cnt) pre = cnt;
    for (int i = rs + tid; i < rs + pre; i += 1024) {
        unsigned w = staging[i]; float2 pv = p[w >> BSHIFT];
        AGG2(w, pv)
    }
    int vs = rs + pre;
    int nq = (re - vs) >> 2;
    const uint4* sv = reinterpret_cast<const uint4*>(staging + vs);
    int qtr = nq >> 2;                            // 4 quarter-streams -> 16 gathers in flight
    for (int q = tid; q < qtr; q += 1024) {
        uint4 wa = sv[q];
        uint4 wb = sv[q + qtr];
        uint4 wc = sv[q + 2 * qtr];
        uint4 wd = sv[q + 3 * qtr];
        float2 a0 = p[wa.x >> BSHIFT], a1 = p[wa.y >> BSHIFT];
        float2 a2 = p[wa.z >> BSHIFT], a3 = p[wa.w >> BSHIFT];
        float2 b0 = p[wb.x >> BSHIFT], b1 = p[wb.y >> BSHIFT];
        float2 b2 = p[wb.z >> BSHIFT], b3 = p[wb.w >> BSHIFT];
        float2 c0 = p[wc.x >> BSHIFT], c1 = p[wc.y >> BSHIFT];
        float2 c2 = p[wc.z >> BSHIFT], c3 = p[wc.w >> BSHIFT];
        float2 d0 = p[wd.x >> BSHIFT], d1 = p[wd.y >> BSHIFT];
        float2 d2 = p[wd.z >> BSHIFT], d3 = p[wd.w >> BSHIFT];
        AGG2(wa.x, a0) AGG2(wa.y, a1) AGG2(wa.z, a2) AGG2(wa.w, a3)
        AGG2(wb.x, b0) AGG2(wb.y, b1) AGG2(wb.z, b2) AGG2(wb.w, b3)
        AGG2(wc.x, c0) AGG2(wc.y, c1) AGG2(wc.z, c2) AGG2(wc.w, c3)
        AGG2(wd.x, d0) AGG2(wd.y, d1) AGG2(wd.z, d2) AGG2(wd.w, d3)
    }
    for (int q = (qtr << 2) + tid; q < nq; q += 1024) {
        uint4 w = sv[q];
        float2 p0 = p[w.x >> BSHIFT], p1 = p[w.y >> BSHIFT];
        float2 p2 = p[w.z >> BSHIFT], p3 = p[w.w >> BSHIFT];
        AGG2(w.x, p0) AGG2(w.y, p1) AGG2(w.z, p2) AGG2(w.w, p3)
    }
    for (int i = vs + (nq << 2) + tid; i < re; i += 1024) {
        unsigned w = staging[i]; float2 pv = p[w >> BSHIFT];
        AGG2(w, pv)
    }
}

// per-bucket aggregation over seg-sorted ranges + fused epilogue
__global__ __launch_bounds__(1024) void k_aggfin(
        const unsigned* __restrict__ staging, const int* __restrict__ gbase,
        const int* __restrict__ soff, const float2* __restrict__ p,
        const float* __restrict__ x, const int* __restrict__ deg,
        const int* __restrict__ batch, const float* __restrict__ Pp, int n,
        float* __restrict__ gsum, float* __restrict__ gcnt) {
    __shared__ float acc[2 * BRANGE];             // 32 KB
    int tid = threadIdx.x;
    for (int j = tid; j < 2 * BRANGE; j += 1024) acc[j] = 0.f;
    __syncthreads();
    int gb = gbase[blockIdx.x];
    if (soff) {
        const int* so = soff + blockIdx.x * (NSEG + 1);
        for (int s = 0; s < NSEG; ++s)
            agg_range(staging, gb + so[s], gb + so[s + 1], p, acc, tid);
    } else {
        agg_range(staging, gb, gbase[blockIdx.x + 1], p, acc, tid);
    }
    __syncthreads();

    // ---- fused epilogue: per-node finish + scatter_mean ----
    float A00 = Pp[0], A01 = Pp[1], A10 = Pp[2], A11 = Pp[3], q0f = Pp[4], q1f = Pp[5];
    float g00 = Pp[6], g01 = Pp[7], g10 = Pp[8], g11 = Pp[9];
    float gb0 = Pp[10], gb1 = Pp[11];
    float S00 = Pp[12], S01 = Pp[13], S11 = Pp[14], Sb0 = Pp[15], Sb1 = Pp[16], Sbb = Pp[17];
    float M00 = Pp[18], M01 = Pp[19], M10 = Pp[20], M11 = Pp[21];
    float t0 = Pp[22], t1 = Pp[23], fb0 = Pp[24], fb1 = Pp[25];
    int nb = blockIdx.x << BSHIFT;
    int lim = n - nb; if (lim > BRANGE) lim = BRANGE;
    for (int j = tid; j < lim; j += 1024) {
        int i = nb + j;
        float2 v = reinterpret_cast<const float2*>(x)[i];
        float g0 = fmaxf(fmaf(A00, v.x, fmaf(A01, v.y, q0f)), 0.f);
        float g1 = fmaxf(fmaf(A10, v.x, fmaf(A11, v.y, q1f)), 0.f);
        float hw0 = g00 * g0 + g01 * g1;
        float hw1 = g10 * g0 + g11 * g1;
        float degf = (float)deg[i] + 1.0f;
        float dis = rsqrtf(degf);
        float a0v = acc[2 * j], a1v = acc[2 * j + 1];
        float c0 = dis * a0v + hw0 / degf + gb0 + g0;
        float c1 = dis * a1v + hw1 / degf + gb1 + g1;
        float vq = S00 * c0 * c0 + 2.f * S01 * c0 * c1 + S11 * c1 * c1
                 + 2.f * Sb0 * c0 + 2.f * Sb1 * c1 + Sbb;
        float inv = rsqrtf(vq + 64.0f);   // eps = H = 64 (arg-order quirk)
        float o0 = inv * (M00 * c0 + M01 * c1 + t0) + fb0;
        float o1 = inv * (M10 * c0 + M11 * c1 + t1) + fb1;
        int bg = batch[i];
        int b0 = __shfl(bg, 0);
        if (__all(bg == b0)) {
            float s0 = o0, s1 = o1;
            for (int off = 32; off; off >>= 1) {
                s0 += __shfl_down(s0, off);
                s1 += __shfl_down(s1, off);
            }
            if ((tid & 63) == 0) {
                atomicAdd(&gsum[2 * b0], s0);
                atomicAdd(&gsum[2 * b0 + 1], s1);
                atomicAdd(&gcnt[b0], 64.0f);
            }
        } else {
            atomicAdd(&gsum[2 * bg], o0);
            atomicAdd(&gsum[2 * bg + 1], o1);
            atomicAdd(&gcnt[bg], 1.0f);
        }
    }
}

__global__ void k_div(const float* __restrict__ gsum, const float* __restrict__ gcnt,
                      float* __restrict__ out, int G) {
    int g = blockIdx.x * blockDim.x + threadIdx.x;
    if (g < G) {
        float c = fmaxf(gcnt[g], 1.0f);
        out[2 * g]     = gsum[2 * g] / c;
        out[2 * g + 1] = gsum[2 * g + 1] / c;
    }
}

// ======================= fallback (global-atomic) kernels =======================

__global__ void k_stats(const float* __restrict__ x, int n, double* __restrict__ partials) {
    float s0 = 0.f, s1 = 0.f, s2 = 0.f, s3 = 0.f, s4 = 0.f;
    int nv = n >> 1;
    int stride = gridDim.x * blockDim.x;
    for (int i = blockIdx.x * blockDim.x + threadIdx.x; i < nv; i += stride) {
        float4 v = reinterpret_cast<const float4*>(x)[i];
        s0 += v.x + v.z; s1 += v.y + v.w;
        s2 += v.x * v.x + v.z * v.z;
        s3 += v.y * v.y + v.w * v.w;
        s4 += v.x * v.y + v.z * v.w;
    }
    if (blockIdx.x == 0 && threadIdx.x == 0 && (n & 1)) {
        float2 v = reinterpret_cast<const float2*>(x)[n - 1];
        s0 += v.x; s1 += v.y; s2 += v.x * v.x; s3 += v.y * v.y; s4 += v.x * v.y;
    }
    for (int off = 32; off; off >>= 1) {
        s0 += __shfl_down(s0, off);
        s1 += __shfl_down(s1, off);
        s2 += __shfl_down(s2, off);
        s3 += __shfl_down(s3, off);
        s4 += __shfl_down(s4, off);
    }
    __shared__ double lds[4][5];
    int wid = threadIdx.x >> 6;
    if ((threadIdx.x & 63) == 0) {
        lds[wid][0] = s0; lds[wid][1] = s1; lds[wid][2] = s2;
        lds[wid][3] = s3; lds[wid][4] = s4;
    }
    __syncthreads();
    if (threadIdx.x == 0) {
        double t0 = 0, t1 = 0, t2 = 0, t3 = 0, t4 = 0;
        for (int w = 0; w < 4; ++w) {
            t0 += lds[w][0]; t1 += lds[w][1]; t2 += lds[w][2];
            t3 += lds[w][3]; t4 += lds[w][4];
        }
        double* o = partials + (size_t)blockIdx.x * 5;
        o[0] = t0; o[1] = t1; o[2] = t2; o[3] = t3; o[4] = t4;
    }
}

__global__ void k_prep(const float* __restrict__ x, const int* __restrict__ deg,
                       const float* __restrict__ P, int n, float2* __restrict__ p) {
    int stride = gridDim.x * blockDim.x;
    float A00 = P[0], A01 = P[1], A10 = P[2], A11 = P[3], q0 = P[4], q1 = P[5];
    float g00 = P[6], g01 = P[7], g10 = P[8], g11 = P[9];
    for (int i = blockIdx.x * blockDim.x + threadIdx.x; i < n; i += stride) {
        float2 v = reinterpret_cast<const float2*>(x)[i];
        float g0 = fmaxf(fmaf(A00, v.x, fmaf(A01, v.y, q0)), 0.f);
        float g1 = fmaxf(fmaf(A10, v.x, fmaf(A11, v.y, q1)), 0.f);
        float hw0 = g00 * g0 + g01 * g1;
        float hw1 = g10 * g0 + g11 * g1;
        float degf = (float)deg[i] + 1.0f;
        float dis = rsqrtf(degf);
        p[i] = make_float2(dis * hw0, dis * hw1);
    }
}

__global__ void k_deg(const int* __restrict__ col, int E, int* __restrict__ deg) {
    int nq = (E + 3) >> 2;
    int q = blockIdx.x * blockDim.x + threadIdx.x;
    if (q >= nq) return;
    int base = q << 2;
    if (base + 3 < E) {
        int4 c = reinterpret_cast<const int4*>(col)[q];
        atomicAdd(&deg[c.x], 1); atomicAdd(&deg[c.y], 1);
        atomicAdd(&deg[c.z], 1); atomicAdd(&deg[c.w], 1);
    } else {
        for (int e = base; e < E; ++e) atomicAdd(&deg[col[e]], 1);
    }
}

__global__ void k_edge(const int* __restrict__ row, const int* __restrict__ col, int E,
                       const float2* __restrict__ p, float* __restrict__ agg) {
    int nq = (E + 3) >> 2;
    int q = blockIdx.x * blockDim.x + threadIdx.x;
    if (q >= nq) return;
    int base = q << 2;
    if (base + 3 < E) {
        int4 r = reinterpret_cast<const int4*>(row)[q];
        int4 c = reinterpret_cast<const int4*>(col)[q];
        float2 p0 = p[r.x], p1 = p[r.y], p2 = p[r.z], p3 = p[r.w];
        atomicAdd(&agg[2 * c.x], p0.x); atomicAdd(&agg[2 * c.x + 1], p0.y);
        atomicAdd(&agg[2 * c.y], p1.x); atomicAdd(&agg[2 * c.y + 1], p1.y);
        atomicAdd(&agg[2 * c.z], p2.x); atomicAdd(&agg[2 * c.z + 1], p2.y);
        atomicAdd(&agg[2 * c.w], p3.x); atomicAdd(&agg[2 * c.w + 1], p3.y);
    } else {
        for (int e = base; e < E; ++e) {
            float2 pv = p[row[e]];
            atomicAdd(&agg[2 * col[e]], pv.x);
            atomicAdd(&agg[2 * col[e] + 1], pv.y);
        }
    }
}

__global__ void k_final(const float* __restrict__ x, const int* __restrict__ deg,
                        const float* __restrict__ agg, const int* __restrict__ batch,
                        const float* __restrict__ P, int n,
                        float* __restrict__ gsum, float* __restrict__ gcnt) {
    int i = blockIdx.x * blockDim.x + threadIdx.x;
    bool valid = i < n;
    float A00 = P[0], A01 = P[1], A10 = P[2], A11 = P[3], q0 = P[4], q1 = P[5];
    float g00 = P[6], g01 = P[7], g10 = P[8], g11 = P[9];
    float gb0 = P[10], gb1 = P[11];
    float S00 = P[12], S01 = P[13], S11 = P[14], Sb0 = P[15], Sb1 = P[16], Sbb = P[17];
    float M00 = P[18], M01 = P[19], M10 = P[20], M11 = P[21];
    float t0 = P[22], t1 = P[23], fb0 = P[24], fb1 = P[25];

    float o0 = 0.f, o1 = 0.f;
    int b = 0;
    if (valid) {
        float2 v = reinterpret_cast<const float2*>(x)[i];
        float g0 = fmaxf(fmaf(A00, v.x, fmaf(A01, v.y, q0)), 0.f);
        float g1 = fmaxf(fmaf(A10, v.x, fmaf(A11, v.y, q1)), 0.f);
        float hw0 = g00 * g0 + g01 * g1;
        float hw1 = g10 * g0 + g11 * g1;
        float degf = (float)deg[i] + 1.0f;
        float dis = rsqrtf(degf);
        float a0 = agg[2 * i], a1 = agg[2 * i + 1];
        float c0 = dis * a0 + hw0 / degf + gb0 + g0;
        float c1 = dis * a1 + hw1 / degf + gb1 + g1;
        float vq = S00 * c0 * c0 + 2.f * S01 * c0 * c1 + S11 * c1 * c1
                 + 2.f * Sb0 * c0 + 2.f * Sb1 * c1 + Sbb;
        float inv = rsqrtf(vq + 64.0f);
        o0 = inv * (M00 * c0 + M01 * c1 + t0) + fb0;
        o1 = inv * (M10 * c0 + M11 * c1 + t1) + fb1;
        b = batch[i];
    }
    unsigned long long act = __ballot(valid);
    if (act == ~0ull) {
        int b0 = __shfl(b, 0);
        if (__all(b == b0)) {
            float s0 = o0, s1 = o1;
            for (int off = 32; off; off >>= 1) {
                s0 += __shfl_down(s0, off);
                s1 += __shfl_down(s1, off);
            }
            if ((threadIdx.x & 63) == 0) {
                atomicAdd(&gsum[2 * b0], s0);
                atomicAdd(&gsum[2 * b0 + 1], s1);
                atomicAdd(&gcnt[b0], 64.0f);
            }
        } else {
            atomicAdd(&gsum[2 * b], o0);
            atomicAdd(&gsum[2 * b + 1], o1);
            atomicAdd(&gcnt[b], 1.0f);
        }
    } else if (valid) {
        atomicAdd(&gsum[2 * b], o0);
        atomicAdd(&gsum[2 * b + 1], o1);
        atomicAdd(&gcnt[b], 1.0f);
    }
}

// ======================= launcher =======================

extern "C" void kernel_launch(void* const* d_in, const int* in_sizes, int n_in,
                              void* d_out, int out_size, void* d_ws, size_t ws_size,
                              hipStream_t stream) {
    const float* x      = (const float*)d_in[0];
    const float* lin_w  = (const float*)d_in[1];
    const float* lin_b  = (const float*)d_in[2];
    const float* gn_w   = (const float*)d_in[3];
    const float* gn_b   = (const float*)d_in[4];
    const float* gn_ms  = (const float*)d_in[5];
    const float* gcn_w  = (const float*)d_in[6];
    const float* gcn_b  = (const float*)d_in[7];
    const float* fc1_w  = (const float*)d_in[8];
    const float* fc1_b  = (const float*)d_in[9];
    const float* fc2_w  = (const float*)d_in[10];
    const float* fc2_b  = (const float*)d_in[11];
    const int*   ei     = (const int*)d_in[12];   // [2, E] row-major
    const int*   batch  = (const int*)d_in[13];

    int n = in_sizes[0] / 2;
    int E = in_sizes[12] / 2;
    int G = out_size / 2;
    const int* row = ei;
    const int* col = ei + E;

    char* ws = (char*)d_ws;
    int nb_nodes = (n + BLK - 1) / BLK;
    int NB = (n + BRANGE - 1) >> BSHIFT;
    int segshift = 0;
    while (((unsigned)(n - 1) >> segshift) >= (unsigned)NSEG) ++segshift;

    // fast-path layout
    size_t zero_end  = 16384 + (size_t)12 * G;               // hdr + gsum + gcnt
    size_t part_off  = (zero_end + 255) & ~(size_t)255;
    size_t soff_off  = (part_off + (size_t)40 * NSB + 255) & ~(size_t)255;
    size_t deg_off   = (soff_off + (size_t)4 * (NSEG + 1) * (NB + 1) + 255) & ~(size_t)255;
    size_t p_off     = deg_off + (size_t)4 * n;
    size_t stag_off  = p_off + (size_t)8 * n;
    size_t stag2_off = stag_off + (size_t)4 * E;
    size_t need      = stag2_off + (size_t)4 * E;

    int do_sort = 1;
    if (need > ws_size) { do_sort = 0; need = stag_off + (size_t)4 * E; }

    bool fast = (n <= (1 << 20)) && (NB <= 253) && (need <= ws_size) &&
                (zero_end <= 16384 + 12288);

    if (fast) {
        float*    P        = (float*)(ws + 64);
        int*      bhist    = (int*)(ws + 4096);
        int*      gbase    = (int*)(ws + 8192);
        int*      cursor   = (int*)(ws + 12288);
        float*    gsum     = (float*)(ws + 16384);
        float*    gcnt     = (float*)(ws + 16384 + (size_t)8 * G);
        double*   part     = (double*)(ws + part_off);
        int*      soff     = (int*)(ws + soff_off);
        int*      deg      = (int*)(ws + deg_off);
        float2*   p        = (float2*)(ws + p_off);
        unsigned* staging  = (unsigned*)(ws + stag_off);
        unsigned* staging2 = do_sort ? (unsigned*)(ws + stag2_off) : (unsigned*)(ws + stag_off);

        hipMemsetAsync(d_ws, 0, zero_end, stream);

        int nbinA = (E + CH - 1) / CH;

        k_stats_hist<<<NSB, BLK, 0, stream>>>(x, n, col, E, NB, part, bhist);
        k_params<<<1, 256, 0, stream>>>(part, NSB, bhist, NB, gbase, cursor,
                                        lin_w, lin_b, gn_w, gn_b, gn_ms,
                                        gcn_w, gcn_b, fc1_w, fc1_b, fc2_w, fc2_b, n, P);
        k_binA<<<nbinA, 256, 0, stream>>>(row, col, E, NB, cursor, staging);
        k_degprep<<<NB, 1024, 0, stream>>>(staging, gbase, x, P, n, segshift, do_sort,
                                           staging2, soff, deg, p);
        k_aggfin<<<NB, 1024, 0, stream>>>(staging2, gbase, do_sort ? soff : (int*)nullptr,
                                          p, x, deg, batch, P, n, gsum, gcnt);
        k_div<<<(G + BLK - 1) / BLK, BLK, 0, stream>>>(gsum, gcnt, (float*)d_out, G);
    } else {
        // fallback: global-atomic path
        float*  P     = (float*)(ws + 64);
        float*  gsum  = (float*)(ws + 4096);
        float*  gcnt  = (float*)(ws + 4096 + (size_t)8 * G);
        size_t fzero_end = 4096 + (size_t)12 * G;
        size_t fpart_off = (fzero_end + 255) & ~(size_t)255;
        size_t fdeg_off  = (fpart_off + (size_t)40 * NSB + 255) & ~(size_t)255;
        int*    deg   = (int*)(ws + fdeg_off);
        size_t fagg_off = fdeg_off + (size_t)4 * n;
        float*  agg   = (float*)(ws + fagg_off);
        size_t fp_off = fagg_off + (size_t)8 * n;
        float2* p     = (float2*)(ws + fp_off);
        double* part  = (double*)(ws + fpart_off);

        hipMemsetAsync(ws + 4096, 0, fzero_end - 4096, stream);
        hipMemsetAsync(ws + fdeg_off, 0, (size_t)12 * n, stream);

        int nq = (E + 3) >> 2;
        int nb_edge = (nq + BLK - 1) / BLK;

        k_stats<<<NSB, BLK, 0, stream>>>(x, n, part);
        k_deg<<<nb_edge, BLK, 0, stream>>>(col, E, deg);
        k_params<<<1, 256, 0, stream>>>(part, NSB, (const int*)nullptr, 0,
                                        (int*)nullptr, (int*)nullptr,
                                        lin_w, lin_b, gn_w, gn_b, gn_ms,
                                        gcn_w, gcn_b, fc1_w, fc1_b, fc2_w, fc2_b, n, P);
        k_prep<<<nb_nodes, BLK, 0, stream>>>(x, deg, P, n, p);
        k_edge<<<nb_edge, BLK, 0, stream>>>(row, col, E, p, agg);
        k_final<<<nb_nodes, BLK, 0, stream>>>(x, deg, agg, batch, P, n, gsum, gcnt);
        k_div<<<(G + BLK - 1) / BLK, BLK, 0, stream>>>(gsum, gcnt, (float*)d_out, G);
    }
}

// Round 13
// 368.548 us; speedup vs baseline: 1.5916x; 1.2966x over previous
//
#include <hip/hip_runtime.h>

#define BLK 256
#define CH 8192           // edges per k_binA block (32 KB LDS sort buffer)
#define BSHIFT 12         // bucket = col >> 12, 4096 nodes per bucket
#define BRANGE 4096
#define BMASK 4095
#define NSB 512           // stats partial blocks

// ============ fused stats + col-bucket histogram (one pass over memory) ============

__global__ void k_stats_hist(const float* __restrict__ x, int n,
                             const int* __restrict__ col, int E, int NB,
                             double* __restrict__ partials, int* __restrict__ bhist) {
    __shared__ int h[256];
    for (int j = threadIdx.x; j < 256; j += blockDim.x) h[j] = 0;
    __syncthreads();
    int stride = gridDim.x * blockDim.x;
    int gtid = blockIdx.x * blockDim.x + threadIdx.x;

    int nqe = E >> 2;
    for (int q = gtid; q < nqe; q += stride) {
        int4 c = reinterpret_cast<const int4*>(col)[q];
        atomicAdd(&h[c.x >> BSHIFT], 1);
        atomicAdd(&h[c.y >> BSHIFT], 1);
        atomicAdd(&h[c.z >> BSHIFT], 1);
        atomicAdd(&h[c.w >> BSHIFT], 1);
    }
    if (blockIdx.x == 0) {
        for (int e = (nqe << 2) + threadIdx.x; e < E; e += blockDim.x)
            atomicAdd(&h[col[e] >> BSHIFT], 1);
    }

    float s0 = 0.f, s1 = 0.f, s2 = 0.f, s3 = 0.f, s4 = 0.f;
    int nv = n >> 1;
    for (int i = gtid; i < nv; i += stride) {
        float4 v = reinterpret_cast<const float4*>(x)[i];
        s0 += v.x + v.z; s1 += v.y + v.w;
        s2 += v.x * v.x + v.z * v.z;
        s3 += v.y * v.y + v.w * v.w;
        s4 += v.x * v.y + v.z * v.w;
    }
    if (blockIdx.x == 0 && threadIdx.x == 0 && (n & 1)) {
        float2 v = reinterpret_cast<const float2*>(x)[n - 1];
        s0 += v.x; s1 += v.y; s2 += v.x * v.x; s3 += v.y * v.y; s4 += v.x * v.y;
    }
    for (int off = 32; off; off >>= 1) {
        s0 += __shfl_down(s0, off);
        s1 += __shfl_down(s1, off);
        s2 += __shfl_down(s2, off);
        s3 += __shfl_down(s3, off);
        s4 += __shfl_down(s4, off);
    }
    __shared__ double lds[4][5];
    int wid = threadIdx.x >> 6;
    if ((threadIdx.x & 63) == 0) {
        lds[wid][0] = s0; lds[wid][1] = s1; lds[wid][2] = s2;
        lds[wid][3] = s3; lds[wid][4] = s4;
    }
    __syncthreads();
    if (threadIdx.x == 0) {
        double t0 = 0, t1 = 0, t2 = 0, t3 = 0, t4 = 0;
        for (int w = 0; w < 4; ++w) {
            t0 += lds[w][0]; t1 += lds[w][1]; t2 += lds[w][2];
            t3 += lds[w][3]; t4 += lds[w][4];
        }
        double* o = partials + (size_t)blockIdx.x * 5;
        o[0] = t0; o[1] = t1; o[2] = t2; o[3] = t3; o[4] = t4;
    }
    for (int j = threadIdx.x; j < NB; j += blockDim.x)
        if (h[j]) atomicAdd(&bhist[j], h[j]);
}

// ===== params: partial reduce + closed-form math + 245-bin scan (fused) =====

__global__ void k_params(const double* __restrict__ partials, int np,
                         const int* __restrict__ bhist, int NB,
                         int* __restrict__ gbase, int* __restrict__ cursor,
                         const float* lin_w, const float* lin_b,
                         const float* gn_w, const float* gn_b, const float* gn_ms,
                         const float* gcn_w, const float* gcn_b,
                         const float* fc1_w, const float* fc1_b,
                         const float* fc2_w, const float* fc2_b,
                         int n, float* __restrict__ P) {
    int tid = threadIdx.x;
    if (bhist) {
        __shared__ int si[256];
        int hv = (tid < NB) ? bhist[tid] : 0;
        si[tid] = hv; __syncthreads();
        for (int off = 1; off < 256; off <<= 1) {
            int t = (tid >= off) ? si[tid - off] : 0;
            __syncthreads();
            si[tid] += t;
            __syncthreads();
        }
        if (tid < NB) { gbase[tid] = si[tid] - hv; cursor[tid] = si[tid] - hv; }
        if (tid == 0) gbase[NB] = si[255];
        __syncthreads();
    }
    double a0 = 0, a1 = 0, a2 = 0, a3 = 0, a4 = 0;
    for (int i = tid; i < np; i += blockDim.x) {
        const double* q = partials + (size_t)i * 5;
        a0 += q[0]; a1 += q[1]; a2 += q[2]; a3 += q[3]; a4 += q[4];
    }
    for (int off = 32; off; off >>= 1) {
        a0 += __shfl_down(a0, off);
        a1 += __shfl_down(a1, off);
        a2 += __shfl_down(a2, off);
        a3 += __shfl_down(a3, off);
        a4 += __shfl_down(a4, off);
    }
    __shared__ double red[4][5];
    int wid = tid >> 6;
    if ((tid & 63) == 0) {
        red[wid][0] = a0; red[wid][1] = a1; red[wid][2] = a2;
        red[wid][3] = a3; red[wid][4] = a4;
    }
    __syncthreads();
    if (tid != 0) return;
    double Sx0 = 0, Sx1 = 0, Sxx = 0, Syy = 0, Sxy = 0;
    for (int w = 0; w < 4; ++w) {
        Sx0 += red[w][0]; Sx1 += red[w][1]; Sxx += red[w][2];
        Syy += red[w][3]; Sxy += red[w][4];
    }
    double N = (double)n;
    for (int c = 0; c < 2; ++c) {
        double L0 = lin_w[c * 2], L1 = lin_w[c * 2 + 1], lb = lin_b[c];
        double m   = (L0 * Sx0 + L1 * Sx1) / N + lb;
        double Eh2 = (L0 * L0 * Sxx + L1 * L1 * Syy + 2.0 * L0 * L1 * Sxy
                      + 2.0 * lb * (L0 * Sx0 + L1 * Sx1)) / N + lb * lb;
        double s   = gn_ms[c];
        double var = Eh2 - 2.0 * s * m * m + s * s * m * m;
        double inv = 1.0 / sqrt(var + 2.0);   // eps = D = 2 (arg-order quirk)
        double gam = gn_w[c];
        P[c * 2 + 0] = (float)(gam * inv * L0);
        P[c * 2 + 1] = (float)(gam * inv * L1);
        P[4 + c]     = (float)(gam * inv * (lb - m * s) + gn_b[c]);
    }
    P[6] = gcn_w[0]; P[7] = gcn_w[1]; P[8] = gcn_w[2]; P[9] = gcn_w[3];
    P[10] = gcn_b[0]; P[11] = gcn_b[1];
    double b0 = 0, b1 = 0, bb = 0;
    for (int j = 0; j < 64; ++j) { b0 += fc1_w[2 * j]; b1 += fc1_w[2 * j + 1]; bb += fc1_b[j]; }
    b0 /= 64.0; b1 /= 64.0; bb /= 64.0;
    double S00 = 0, S01 = 0, S11 = 0, Sb0 = 0, Sb1 = 0, Sbb = 0;
    double M00 = 0, M01 = 0, M10 = 0, M11 = 0, t0 = 0, t1 = 0;
    for (int j = 0; j < 64; ++j) {
        double w0 = fc1_w[2 * j] - b0, w1 = fc1_w[2 * j + 1] - b1, b = fc1_b[j] - bb;
        S00 += w0 * w0; S01 += w0 * w1; S11 += w1 * w1;
        Sb0 += w0 * b;  Sb1 += w1 * b;  Sbb += b * b;
        double f0 = fc2_w[j], f1 = fc2_w[64 + j];
        M00 += f0 * w0; M01 += f0 * w1; t0 += f0 * b;
        M10 += f1 * w0; M11 += f1 * w1; t1 += f1 * b;
    }
    P[12] = (float)(S00 / 64.0); P[13] = (float)(S01 / 64.0); P[14] = (float)(S11 / 64.0);
    P[15] = (float)(Sb0 / 64.0); P[16] = (float)(Sb1 / 64.0); P[17] = (float)(Sbb / 64.0);
    P[18] = (float)M00; P[19] = (float)M01; P[20] = (float)M10; P[21] = (float)M11;
    P[22] = (float)t0;  P[23] = (float)t1;
    P[24] = fc2_b[0];   P[25] = fc2_b[1];
}

// ======================= binning pipeline =======================

__global__ void k_hist(const int* __restrict__ col, int E, int NB, int* __restrict__ bhist) {
    __shared__ int h[256];
    for (int j = threadIdx.x; j < 256; j += blockDim.x) h[j] = 0;
    __syncthreads();
    int nq = E >> 2;
    int stride = gridDim.x * blockDim.x;
    for (int q = blockIdx.x * blockDim.x + threadIdx.x; q < nq; q += stride) {
        int4 c = reinterpret_cast<const int4*>(col)[q];
        atomicAdd(&h[c.x >> BSHIFT], 1);
        atomicAdd(&h[c.y >> BSHIFT], 1);
        atomicAdd(&h[c.z >> BSHIFT], 1);
        atomicAdd(&h[c.w >> BSHIFT], 1);
    }
    if (blockIdx.x == 0) {
        for (int e = (nq << 2) + threadIdx.x; e < E; e += blockDim.x)
            atomicAdd(&h[col[e] >> BSHIFT], 1);
    }
    __syncthreads();
    for (int j = threadIdx.x; j < NB; j += blockDim.x)
        if (h[j]) atomicAdd(&bhist[j], h[j]);
}

// block-local counting sort -> coalesced bucket-contiguous write-out
__global__ __launch_bounds__(256) void k_binA(const int* __restrict__ row,
                                              const int* __restrict__ col, int E,
                                              int NB, int* __restrict__ cursor,
                                              unsigned* __restrict__ staging) {
    __shared__ unsigned buf[CH];                  // 32 KB
    __shared__ int h[256], si[256], lpos[256], lcur[256];
    int tid = threadIdx.x;
    int start = blockIdx.x * CH;
    int end = start + CH; if (end > E) end = E;
    h[tid] = 0;
    __syncthreads();
    for (int e = start + tid; e < end; e += 256)
        atomicAdd(&h[col[e] >> BSHIFT], 1);
    __syncthreads();
    int hv = h[tid];
    si[tid] = hv; __syncthreads();
    for (int off = 1; off < 256; off <<= 1) {     // Hillis-Steele inclusive scan
        int t = (tid >= off) ? si[tid - off] : 0;
        __syncthreads();
        si[tid] += t;
        __syncthreads();
    }
    lpos[tid] = si[tid] - hv;
    lcur[tid] = (tid < NB && hv) ? atomicAdd(&cursor[tid], hv) : 0;
    __syncthreads();
    for (int e = start + tid; e < end; e += 256) {
        int c = col[e];
        unsigned w = ((unsigned)row[e] << BSHIFT) | (unsigned)(c & BMASK);
        int slot = atomicAdd(&lpos[c >> BSHIFT], 1);
        buf[slot] = w;
    }
    __syncthreads();
    int wid = tid >> 6, lane = tid & 63;
    for (int b = wid; b < NB; b += 4) {
        int m = h[b];
        if (!m) continue;
        int lb = si[b] - m;
        int g = lcur[b];
        for (int k = lane; k < m; k += 64)
            staging[g + k] = buf[lb + k];
    }
}

// fused: per-bucket degree histogram + p-prep (node range == bucket range)
__global__ __launch_bounds__(1024) void k_degprep(const unsigned* __restrict__ staging,
                                                  const int* __restrict__ gbase,
                                                  const float* __restrict__ x,
                                                  const float* __restrict__ P,
                                                  int n, int* __restrict__ deg,
                                                  float2* __restrict__ p) {
    __shared__ int hist[BRANGE];
    int tid = threadIdx.x;
    for (int j = tid; j < BRANGE; j += 1024) hist[j] = 0;
    __syncthreads();
    int s = gbase[blockIdx.x], e = gbase[blockIdx.x + 1];
    int pre = (4 - (s & 3)) & 3; int cnt = e - s; if (pre > cnt) pre = cnt;
    for (int i = s + tid; i < s + pre; i += 1024)
        atomicAdd(&hist[staging[i] & BMASK], 1);
    int vs = s + pre;
    int nq = (e - vs) >> 2;
    const uint4* sv = reinterpret_cast<const uint4*>(staging + vs);
    for (int q = tid; q < nq; q += 1024) {
        uint4 w = sv[q];
        atomicAdd(&hist[w.x & BMASK], 1);
        atomicAdd(&hist[w.y & BMASK], 1);
        atomicAdd(&hist[w.z & BMASK], 1);
        atomicAdd(&hist[w.w & BMASK], 1);
    }
    for (int i = vs + (nq << 2) + tid; i < e; i += 1024)
        atomicAdd(&hist[staging[i] & BMASK], 1);
    __syncthreads();
    float A00 = P[0], A01 = P[1], A10 = P[2], A11 = P[3], q0 = P[4], q1 = P[5];
    float g00 = P[6], g01 = P[7], g10 = P[8], g11 = P[9];
    int nb = blockIdx.x << BSHIFT;
    int lim = n - nb; if (lim > BRANGE) lim = BRANGE;
    for (int j = tid; j < lim; j += 1024) {
        int d = hist[j];
        deg[nb + j] = d;
        float2 v = reinterpret_cast<const float2*>(x)[nb + j];
        float gg0 = fmaxf(fmaf(A00, v.x, fmaf(A01, v.y, q0)), 0.f);
        float gg1 = fmaxf(fmaf(A10, v.x, fmaf(A11, v.y, q1)), 0.f);
        float hw0 = g00 * gg0 + g01 * gg1;
        float hw1 = g10 * gg0 + g11 * gg1;
        float degf = (float)d + 1.0f;
        float dis = rsqrtf(degf);
        p[nb + j] = make_float2(dis * hw0, dis * hw1);
    }
}

#define AGG2(W, PV) \
    atomicAdd(&acc[2 * ((W) & BMASK)],     (PV).x); \
    atomicAdd(&acc[2 * ((W) & BMASK) + 1], (PV).y);

// single-pass per-bucket aggregation with 4x-unrolled high-MLP gather + fused epilogue
__global__ __launch_bounds__(1024) void k_aggfin(
        const unsigned* __restrict__ staging, const int* __restrict__ gbase,
        const float2* __restrict__ p, const float* __restrict__ x,
        const int* __restrict__ deg, const int* __restrict__ batch,
        const float* __restrict__ Pp, int n,
        float* __restrict__ gsum, float* __restrict__ gcnt) {
    __shared__ float acc[2 * BRANGE];             // 32 KB
    int tid = threadIdx.x;
    for (int j = tid; j < 2 * BRANGE; j += 1024) acc[j] = 0.f;
    __syncthreads();
    int s = gbase[blockIdx.x], e = gbase[blockIdx.x + 1];
    int cnt = e - s;
    int pre = (4 - (s & 3)) & 3; if (pre > cnt) pre = cnt;
    for (int i = s + tid; i < s + pre; i += 1024) {
        unsigned w = staging[i]; float2 pv = p[w >> BSHIFT];
        AGG2(w, pv)
    }
    int vs = s + pre;
    int nq = (e - vs) >> 2;
    const uint4* sv = reinterpret_cast<const uint4*>(staging + vs);
    // main: 4 quads (16 edges) per iteration -> 16 gathers in flight before atomics
    int q = tid;
    for (; q + 3 * 1024 < nq; q += 4 * 1024) {
        uint4 wa = sv[q];
        uint4 wb = sv[q + 1024];
        uint4 wc = sv[q + 2048];
        uint4 wd = sv[q + 3072];
        float2 a0 = p[wa.x >> BSHIFT], a1 = p[wa.y >> BSHIFT];
        float2 a2 = p[wa.z >> BSHIFT], a3 = p[wa.w >> BSHIFT];
        float2 b0 = p[wb.x >> BSHIFT], b1 = p[wb.y >> BSHIFT];
        float2 b2 = p[wb.z >> BSHIFT], b3 = p[wb.w >> BSHIFT];
        float2 c0 = p[wc.x >> BSHIFT], c1 = p[wc.y >> BSHIFT];
        float2 c2 = p[wc.z >> BSHIFT], c3 = p[wc.w >> BSHIFT];
        float2 d0 = p[wd.x >> BSHIFT], d1 = p[wd.y >> BSHIFT];
        float2 d2 = p[wd.z >> BSHIFT], d3 = p[wd.w >> BSHIFT];
        AGG2(wa.x, a0) AGG2(wa.y, a1) AGG2(wa.z, a2) AGG2(wa.w, a3)
        AGG2(wb.x, b0) AGG2(wb.y, b1) AGG2(wb.z, b2) AGG2(wb.w, b3)
        AGG2(wc.x, c0) AGG2(wc.y, c1) AGG2(wc.z, c2) AGG2(wc.w, c3)
        AGG2(wd.x, d0) AGG2(wd.y, d1) AGG2(wd.z, d2) AGG2(wd.w, d3)
    }
    for (; q < nq; q += 1024) {
        uint4 w = sv[q];
        float2 p0 = p[w.x >> BSHIFT], p1 = p[w.y >> BSHIFT];
        float2 p2 = p[w.z >> BSHIFT], p3 = p[w.w >> BSHIFT];
        AGG2(w.x, p0) AGG2(w.y, p1) AGG2(w.z, p2) AGG2(w.w, p3)
    }
    for (int i = vs + (nq << 2) + tid; i < e; i += 1024) {
        unsigned w = staging[i]; float2 pv = p[w >> BSHIFT];
        AGG2(w, pv)
    }
    __syncthreads();

    // ---- fused epilogue: per-node finish + scatter_mean ----
    float A00 = Pp[0], A01 = Pp[1], A10 = Pp[2], A11 = Pp[3], q0f = Pp[4], q1f = Pp[5];
    float g00 = Pp[6], g01 = Pp[7], g10 = Pp[8], g11 = Pp[9];
    float gb0 = Pp[10], gb1 = Pp[11];
    float S00 = Pp[12], S01 = Pp[13], S11 = Pp[14], Sb0 = Pp[15], Sb1 = Pp[16], Sbb = Pp[17];
    float M00 = Pp[18], M01 = Pp[19], M10 = Pp[20], M11 = Pp[21];
    float t0 = Pp[22], t1 = Pp[23], fb0 = Pp[24], fb1 = Pp[25];
    int nb = blockIdx.x << BSHIFT;
    int lim = n - nb; if (lim > BRANGE) lim = BRANGE;
    for (int j = tid; j < lim; j += 1024) {
        int i = nb + j;
        float2 v = reinterpret_cast<const float2*>(x)[i];
        float g0 = fmaxf(fmaf(A00, v.x, fmaf(A01, v.y, q0f)), 0.f);
        float g1 = fmaxf(fmaf(A10, v.x, fmaf(A11, v.y, q1f)), 0.f);
        float hw0 = g00 * g0 + g01 * g1;
        float hw1 = g10 * g0 + g11 * g1;
        float degf = (float)deg[i] + 1.0f;
        float dis = rsqrtf(degf);
        float a0v = acc[2 * j], a1v = acc[2 * j + 1];
        float c0 = dis * a0v + hw0 / degf + gb0 + g0;
        float c1 = dis * a1v + hw1 / degf + gb1 + g1;
        float vq = S00 * c0 * c0 + 2.f * S01 * c0 * c1 + S11 * c1 * c1
                 + 2.f * Sb0 * c0 + 2.f * Sb1 * c1 + Sbb;
        float inv = rsqrtf(vq + 64.0f);   // eps = H = 64 (arg-order quirk)
        float o0 = inv * (M00 * c0 + M01 * c1 + t0) + fb0;
        float o1 = inv * (M10 * c0 + M11 * c1 + t1) + fb1;
        int bg = batch[i];
        unsigned long long act = __ballot(true);
        if (act == ~0ull) {
            int b0 = __shfl(bg, 0);
            if (__all(bg == b0)) {
                float s0 = o0, s1 = o1;
                for (int off = 32; off; off >>= 1) {
                    s0 += __shfl_down(s0, off);
                    s1 += __shfl_down(s1, off);
                }
                if ((tid & 63) == 0) {
                    atomicAdd(&gsum[2 * b0], s0);
                    atomicAdd(&gsum[2 * b0 + 1], s1);
                    atomicAdd(&gcnt[b0], 64.0f);
                }
            } else {
                atomicAdd(&gsum[2 * bg], o0);
                atomicAdd(&gsum[2 * bg + 1], o1);
                atomicAdd(&gcnt[bg], 1.0f);
            }
        } else {
            atomicAdd(&gsum[2 * bg], o0);
            atomicAdd(&gsum[2 * bg + 1], o1);
            atomicAdd(&gcnt[bg], 1.0f);
        }
    }
}

__global__ void k_div(const float* __restrict__ gsum, const float* __restrict__ gcnt,
                      float* __restrict__ out, int G) {
    int g = blockIdx.x * blockDim.x + threadIdx.x;
    if (g < G) {
        float c = fmaxf(gcnt[g], 1.0f);
        out[2 * g]     = gsum[2 * g] / c;
        out[2 * g + 1] = gsum[2 * g + 1] / c;
    }
}

// ======================= fallback (global-atomic) kernels =======================

__global__ void k_stats(const float* __restrict__ x, int n, double* __restrict__ partials) {
    float s0 = 0.f, s1 = 0.f, s2 = 0.f, s3 = 0.f, s4 = 0.f;
    int nv = n >> 1;
    int stride = gridDim.x * blockDim.x;
    for (int i = blockIdx.x * blockDim.x + threadIdx.x; i < nv; i += stride) {
        float4 v = reinterpret_cast<const float4*>(x)[i];
        s0 += v.x + v.z; s1 += v.y + v.w;
        s2 += v.x * v.x + v.z * v.z;
        s3 += v.y * v.y + v.w * v.w;
        s4 += v.x * v.y + v.z * v.w;
    }
    if (blockIdx.x == 0 && threadIdx.x == 0 && (n & 1)) {
        float2 v = reinterpret_cast<const float2*>(x)[n - 1];
        s0 += v.x; s1 += v.y; s2 += v.x * v.x; s3 += v.y * v.y; s4 += v.x * v.y;
    }
    for (int off = 32; off; off >>= 1) {
        s0 += __shfl_down(s0, off);
        s1 += __shfl_down(s1, off);
        s2 += __shfl_down(s2, off);
        s3 += __shfl_down(s3, off);
        s4 += __shfl_down(s4, off);
    }
    __shared__ double lds[4][5];
    int wid = threadIdx.x >> 6;
    if ((threadIdx.x & 63) == 0) {
        lds[wid][0] = s0; lds[wid][1] = s1; lds[wid][2] = s2;
        lds[wid][3] = s3; lds[wid][4] = s4;
    }
    __syncthreads();
    if (threadIdx.x == 0) {
        double t0 = 0, t1 = 0, t2 = 0, t3 = 0, t4 = 0;
        for (int w = 0; w < 4; ++w) {
            t0 += lds[w][0]; t1 += lds[w][1]; t2 += lds[w][2];
            t3 += lds[w][3]; t4 += lds[w][4];
        }
        double* o = partials + (size_t)blockIdx.x * 5;
        o[0] = t0; o[1] = t1; o[2] = t2; o[3] = t3; o[4] = t4;
    }
}

__global__ void k_prep(const float* __restrict__ x, const int* __restrict__ deg,
                       const float* __restrict__ P, int n, float2* __restrict__ p) {
    int stride = gridDim.x * blockDim.x;
    float A00 = P[0], A01 = P[1], A10 = P[2], A11 = P[3], q0 = P[4], q1 = P[5];
    float g00 = P[6], g01 = P[7], g10 = P[8], g11 = P[9];
    for (int i = blockIdx.x * blockDim.x + threadIdx.x; i < n; i += stride) {
        float2 v = reinterpret_cast<const float2*>(x)[i];
        float g0 = fmaxf(fmaf(A00, v.x, fmaf(A01, v.y, q0)), 0.f);
        float g1 = fmaxf(fmaf(A10, v.x, fmaf(A11, v.y, q1)), 0.f);
        float hw0 = g00 * g0 + g01 * g1;
        float hw1 = g10 * g0 + g11 * g1;
        float degf = (float)deg[i] + 1.0f;
        float dis = rsqrtf(degf);
        p[i] = make_float2(dis * hw0, dis * hw1);
    }
}

__global__ void k_deg(const int* __restrict__ col, int E, int* __restrict__ deg) {
    int nq = (E + 3) >> 2;
    int q = blockIdx.x * blockDim.x + threadIdx.x;
    if (q >= nq) return;
    int base = q << 2;
    if (base + 3 < E) {
        int4 c = reinterpret_cast<const int4*>(col)[q];
        atomicAdd(&deg[c.x], 1); atomicAdd(&deg[c.y], 1);
        atomicAdd(&deg[c.z], 1); atomicAdd(&deg[c.w], 1);
    } else {
        for (int e = base; e < E; ++e) atomicAdd(&deg[col[e]], 1);
    }
}

__global__ void k_edge(const int* __restrict__ row, const int* __restrict__ col, int E,
                       const float2* __restrict__ p, float* __restrict__ agg) {
    int nq = (E + 3) >> 2;
    int q = blockIdx.x * blockDim.x + threadIdx.x;
    if (q >= nq) return;
    int base = q << 2;
    if (base + 3 < E) {
        int4 r = reinterpret_cast<const int4*>(row)[q];
        int4 c = reinterpret_cast<const int4*>(col)[q];
        float2 p0 = p[r.x], p1 = p[r.y], p2 = p[r.z], p3 = p[r.w];
        atomicAdd(&agg[2 * c.x], p0.x); atomicAdd(&agg[2 * c.x + 1], p0.y);
        atomicAdd(&agg[2 * c.y], p1.x); atomicAdd(&agg[2 * c.y + 1], p1.y);
        atomicAdd(&agg[2 * c.z], p2.x); atomicAdd(&agg[2 * c.z + 1], p2.y);
        atomicAdd(&agg[2 * c.w], p3.x); atomicAdd(&agg[2 * c.w + 1], p3.y);
    } else {
        for (int e = base; e < E; ++e) {
            float2 pv = p[row[e]];
            atomicAdd(&agg[2 * col[e]], pv.x);
            atomicAdd(&agg[2 * col[e] + 1], pv.y);
        }
    }
}

__global__ void k_final(const float* __restrict__ x, const int* __restrict__ deg,
                        const float* __restrict__ agg, const int* __restrict__ batch,
                        const float* __restrict__ P, int n,
                        float* __restrict__ gsum, float* __restrict__ gcnt) {
    int i = blockIdx.x * blockDim.x + threadIdx.x;
    bool valid = i < n;
    float A00 = P[0], A01 = P[1], A10 = P[2], A11 = P[3], q0 = P[4], q1 = P[5];
    float g00 = P[6], g01 = P[7], g10 = P[8], g11 = P[9];
    float gb0 = P[10], gb1 = P[11];
    float S00 = P[12], S01 = P[13], S11 = P[14], Sb0 = P[15], Sb1 = P[16], Sbb = P[17];
    float M00 = P[18], M01 = P[19], M10 = P[20], M11 = P[21];
    float t0 = P[22], t1 = P[23], fb0 = P[24], fb1 = P[25];

    float o0 = 0.f, o1 = 0.f;
    int b = 0;
    if (valid) {
        float2 v = reinterpret_cast<const float2*>(x)[i];
        float g0 = fmaxf(fmaf(A00, v.x, fmaf(A01, v.y, q0)), 0.f);
        float g1 = fmaxf(fmaf(A10, v.x, fmaf(A11, v.y, q1)), 0.f);
        float hw0 = g00 * g0 + g01 * g1;
        float hw1 = g10 * g0 + g11 * g1;
        float degf = (float)deg[i] + 1.0f;
        float dis = rsqrtf(degf);
        float a0 = agg[2 * i], a1 = agg[2 * i + 1];
        float c0 = dis * a0 + hw0 / degf + gb0 + g0;
        float c1 = dis * a1 + hw1 / degf + gb1 + g1;
        float vq = S00 * c0 * c0 + 2.f * S01 * c0 * c1 + S11 * c1 * c1
                 + 2.f * Sb0 * c0 + 2.f * Sb1 * c1 + Sbb;
        float inv = rsqrtf(vq + 64.0f);
        o0 = inv * (M00 * c0 + M01 * c1 + t0) + fb0;
        o1 = inv * (M10 * c0 + M11 * c1 + t1) + fb1;
        b = batch[i];
    }
    unsigned long long act = __ballot(valid);
    if (act == ~0ull) {
        int b0 = __shfl(b, 0);
        if (__all(b == b0)) {
            float s0 = o0, s1 = o1;
            for (int off = 32; off; off >>= 1) {
                s0 += __shfl_down(s0, off);
                s1 += __shfl_down(s1, off);
            }
            if ((threadIdx.x & 63) == 0) {
                atomicAdd(&gsum[2 * b0], s0);
                atomicAdd(&gsum[2 * b0 + 1], s1);
                atomicAdd(&gcnt[b0], 64.0f);
            }
        } else {
            atomicAdd(&gsum[2 * b], o0);
            atomicAdd(&gsum[2 * b + 1], o1);
            atomicAdd(&gcnt[b], 1.0f);
        }
    } else if (valid) {
        atomicAdd(&gsum[2 * b], o0);
        atomicAdd(&gsum[2 * b + 1], o1);
        atomicAdd(&gcnt[b], 1.0f);
    }
}

// ======================= launcher =======================

extern "C" void kernel_launch(void* const* d_in, const int* in_sizes, int n_in,
                              void* d_out, int out_size, void* d_ws, size_t ws_size,
                              hipStream_t stream) {
    const float* x      = (const float*)d_in[0];
    const float* lin_w  = (const float*)d_in[1];
    const float* lin_b  = (const float*)d_in[2];
    const float* gn_w   = (const float*)d_in[3];
    const float* gn_b   = (const float*)d_in[4];
    const float* gn_ms  = (const float*)d_in[5];
    const float* gcn_w  = (const float*)d_in[6];
    const float* gcn_b  = (const float*)d_in[7];
    const float* fc1_w  = (const float*)d_in[8];
    const float* fc1_b  = (const float*)d_in[9];
    const float* fc2_w  = (const float*)d_in[10];
    const float* fc2_b  = (const float*)d_in[11];
    const int*   ei     = (const int*)d_in[12];   // [2, E] row-major
    const int*   batch  = (const int*)d_in[13];

    int n = in_sizes[0] / 2;
    int E = in_sizes[12] / 2;
    int G = out_size / 2;
    const int* row = ei;
    const int* col = ei + E;

    char* ws = (char*)d_ws;
    int nb_nodes = (n + BLK - 1) / BLK;
    int NB = (n + BRANGE - 1) >> BSHIFT;

    // fast-path layout (R9)
    size_t zero_end  = 16384 + (size_t)12 * G;               // hdr + gsum + gcnt
    size_t part_off  = (zero_end + 255) & ~(size_t)255;
    size_t deg_off   = (part_off + (size_t)40 * NSB + 255) & ~(size_t)255;
    size_t p_off     = deg_off + (size_t)4 * n;
    size_t stag_off  = p_off + (size_t)8 * n;
    size_t need      = stag_off + (size_t)4 * E;

    bool fast = (n <= (1 << 20)) && (NB <= 253) && (need <= ws_size) &&
                (zero_end <= 16384 + 12288);

    if (fast) {
        float*    P       = (float*)(ws + 64);
        int*      bhist   = (int*)(ws + 4096);
        int*      gbase   = (int*)(ws + 8192);
        int*      cursor  = (int*)(ws + 12288);
        float*    gsum    = (float*)(ws + 16384);
        float*    gcnt    = (float*)(ws + 16384 + (size_t)8 * G);
        double*   part    = (double*)(ws + part_off);
        int*      deg     = (int*)(ws + deg_off);
        float2*   p       = (float2*)(ws + p_off);
        unsigned* staging = (unsigned*)(ws + stag_off);

        hipMemsetAsync(d_ws, 0, zero_end, stream);

        int nbinA = (E + CH - 1) / CH;

        k_stats_hist<<<NSB, BLK, 0, stream>>>(x, n, col, E, NB, part, bhist);
        k_params<<<1, 256, 0, stream>>>(part, NSB, bhist, NB, gbase, cursor,
                                        lin_w, lin_b, gn_w, gn_b, gn_ms,
                                        gcn_w, gcn_b, fc1_w, fc1_b, fc2_w, fc2_b, n, P);
        k_binA<<<nbinA, 256, 0, stream>>>(row, col, E, NB, cursor, staging);
        k_degprep<<<NB, 1024, 0, stream>>>(staging, gbase, x, P, n, deg, p);
        k_aggfin<<<NB, 1024, 0, stream>>>(staging, gbase, p, x, deg, batch,
                                          P, n, gsum, gcnt);
        k_div<<<(G + BLK - 1) / BLK, BLK, 0, stream>>>(gsum, gcnt, (float*)d_out, G);
    } else {
        // fallback: global-atomic path
        float*  P     = (float*)(ws + 64);
        float*  gsum  = (float*)(ws + 4096);
        float*  gcnt  = (float*)(ws + 4096 + (size_t)8 * G);
        size_t fzero_end = 4096 + (size_t)12 * G;
        size_t fpart_off = (fzero_end + 255) & ~(size_t)255;
        size_t fdeg_off  = (fpart_off + (size_t)40 * NSB + 255) & ~(size_t)255;
        int*    deg   = (int*)(ws + fdeg_off);
        size_t fagg_off = fdeg_off + (size_t)4 * n;
        float*  agg   = (float*)(ws + fagg_off);
        size_t fp_off = fagg_off + (size_t)8 * n;
        float2* p     = (float2*)(ws + fp_off);
        double* part  = (double*)(ws + fpart_off);

        hipMemsetAsync(ws + 4096, 0, fzero_end - 4096, stream);
        hipMemsetAsync(ws + fdeg_off, 0, (size_t)12 * n, stream);

        int nq = (E + 3) >> 2;
        int nb_edge = (nq + BLK - 1) / BLK;

        k_stats<<<NSB, BLK, 0, stream>>>(x, n, part);
        k_deg<<<nb_edge, BLK, 0, stream>>>(col, E, deg);
        k_params<<<1, 256, 0, stream>>>(part, NSB, (const int*)nullptr, 0,
                                        (int*)nullptr, (int*)nullptr,
                                        lin_w, lin_b, gn_w, gn_b, gn_ms,
                                        gcn_w, gcn_b, fc1_w, fc1_b, fc2_w, fc2_b, n, P);
        k_prep<<<nb_nodes, BLK, 0, stream>>>(x, deg, P, n, p);
        k_edge<<<nb_edge, BLK, 0, stream>>>(row, col, E, p, agg);
        k_final<<<nb_nodes, BLK, 0, stream>>>(x, deg, agg, batch, P, n, gsum, gcnt);
        k_div<<<(G + BLK - 1) / BLK, BLK, 0, stream>>>(gsum, gcnt, (float*)d_out, G);
    }
}